// Round 5
// baseline (373.977 us; speedup 1.0000x reference)
//
#include <hip/hip_runtime.h>
#include <hip/hip_bf16.h>

typedef __bf16 bf16x8 __attribute__((ext_vector_type(8)));
typedef float  f32x4  __attribute__((ext_vector_type(4)));

__device__ __forceinline__ unsigned short f2bf(float f) {
    union { float f; unsigned int u; } v; v.f = f;
    return (unsigned short)((v.u + 0x8000u) >> 16);   // round-half-up: 2 VALU
}
__device__ __forceinline__ float bf2f(unsigned short h) {
    union { unsigned int u; float f; } v; v.u = ((unsigned int)h) << 16;
    return v.f;
}

typedef __attribute__((address_space(3))) unsigned int lds_u32_t;
typedef const __attribute__((address_space(1))) unsigned int glb_u32_t;
__device__ __forceinline__ void gl_lds16(const void* g, void* l) {
    __builtin_amdgcn_global_load_lds((glb_u32_t*)g, (lds_u32_t*)l, 16, 0, 0);
}

// ---------------- fused casts fp32 -> bf16 (x and c_attn_w in one dispatch) ----------------
__global__ void k_cast2(const float* __restrict__ a, unsigned short* __restrict__ oa,
                        const float* __restrict__ b, unsigned short* __restrict__ ob) {
    int blk = blockIdx.x;
    const float* in;
    unsigned short* out;
    int base;
    if (blk < 8192) { in = a; out = oa; base = blk * 1024; }
    else            { in = b; out = ob; base = (blk - 8192) * 1024; }
    int i = base + threadIdx.x * 4;
    float4 v = *reinterpret_cast<const float4*>(in + i);
    ushort4 o;
    o.x = f2bf(v.x); o.y = f2bf(v.y); o.z = f2bf(v.z); o.w = f2bf(v.w);
    *reinterpret_cast<ushort4*>(out + i) = o;
}

// ---------------- 4x transpose+cast 1024x1024: [K][N] f32 -> [N][K] bf16 ----------------
__global__ void k_transpose4(const float* __restrict__ s0, const float* __restrict__ s1,
                             const float* __restrict__ s2, const float* __restrict__ s3,
                             unsigned short* __restrict__ d0, unsigned short* __restrict__ d1,
                             unsigned short* __restrict__ d2, unsigned short* __restrict__ d3) {
    __shared__ float tile[32][33];
    int z = blockIdx.z;
    const float* in = (z == 0) ? s0 : (z == 1) ? s1 : (z == 2) ? s2 : s3;
    unsigned short* out = (z == 0) ? d0 : (z == 1) ? d1 : (z == 2) ? d2 : d3;
    int n0 = blockIdx.x * 32, k0 = blockIdx.y * 32;
    int tx = threadIdx.x, ty = threadIdx.y; // block (32,8)
    #pragma unroll
    for (int i = 0; i < 4; ++i)
        tile[ty + i * 8][tx] = in[(size_t)(k0 + ty + i * 8) * 1024 + n0 + tx];
    __syncthreads();
    #pragma unroll
    for (int i = 0; i < 4; ++i)
        out[(size_t)(n0 + ty + i * 8) * 1024 + k0 + tx] = f2bf(tile[tx][ty + i * 8]);
}

// ---------------- bf16 MFMA GEMM: A staged (LDS dbuf, 1 barrier/iter), B direct global->reg ----------------
// Swapped mfma(B,A): lane dim = A-row, reg dim = B-col -> 4 consecutive cols per lane -> vector stores.
// B panels are L2-resident (<=2MB): per-wave direct b128 loads halve LDS traffic; B needs no barrier,
// so A(i+1) is issued AFTER the single barrier into the other LDS half (latency hidden under compute).
// mode 0: out bf16 row-major [M,N];  mode 2: out fp32 row-major [M,N]
__global__ __launch_bounds__(256) void k_gemm(
    const unsigned short* __restrict__ A, int lda,
    const unsigned short* __restrict__ Bt, int ldb,
    const float* __restrict__ bias,
    void* __restrict__ out,
    int M, int N, int K, int mode, float scale)
{
    __shared__ unsigned short As[16384];   // [2 buf][2 kk][128][32]
    int tid  = threadIdx.x;
    int lane = tid & 63, wv = tid >> 6;
    int quad = lane >> 4, l16 = lane & 15;

    // XCD-aware chunked swizzle (bijective when nwg % 8 == 0)
    int nwg = gridDim.x * gridDim.y;
    int lin = blockIdx.y * gridDim.x + blockIdx.x;
    int bx = blockIdx.x, by = blockIdx.y;
    if ((nwg & 7) == 0) {
        int swz = (lin & 7) * (nwg >> 3) + (lin >> 3);
        bx = swz % gridDim.x;
        by = swz / gridDim.x;
    }
    int bm = by * 128, bn = bx * 128;
    int wm = (wv >> 1) * 64,  wn = (wv & 1) * 64;

    f32x4 acc[4][4] = {};
    int srow = tid >> 2, scol = (tid & 3) * 8;
    const unsigned short* brow = &Bt[(size_t)(bn + wn + l16) * ldb + quad * 8];

    // prologue: stage A(0) into buf0
    #pragma unroll
    for (int kk = 0; kk < 2; ++kk)
        #pragma unroll
        for (int s = 0; s < 2; ++s) {
            int row = s * 64 + srow;
            gl_lds16(&A[(size_t)(bm + row) * lda + kk * 32 + scol], &As[kk * 4096 + (s * 256 + wv * 64) * 8]);
        }

    int nk = K >> 6;
    for (int i = 0; i < nk; ++i) {
        int k0 = i << 6;
        int cur = (i & 1) * 8192;
        bf16x8 bfv[2][4];
        #pragma unroll
        for (int kk = 0; kk < 2; ++kk)
            #pragma unroll
            for (int ni = 0; ni < 4; ++ni)
                bfv[kk][ni] = *reinterpret_cast<const bf16x8*>(&brow[(size_t)ni * 16 * ldb + k0 + kk * 32]);
        __syncthreads();   // drains A(i) (issued last iter) + B(i) (just issued, L2-fast)
        if (i + 1 < nk) {
            int nxt = ((i + 1) & 1) * 8192;
            #pragma unroll
            for (int kk = 0; kk < 2; ++kk)
                #pragma unroll
                for (int s = 0; s < 2; ++s) {
                    int row = s * 64 + srow;
                    gl_lds16(&A[(size_t)(bm + row) * lda + k0 + 64 + kk * 32 + scol],
                             &As[nxt + kk * 4096 + (s * 256 + wv * 64) * 8]);
                }
        }
        #pragma unroll
        for (int kk = 0; kk < 2; ++kk) {
            bf16x8 af[4];
            #pragma unroll
            for (int mi = 0; mi < 4; ++mi)
                af[mi] = *reinterpret_cast<const bf16x8*>(&As[cur + kk * 4096 + (wm + mi * 16 + l16) * 32 + quad * 8]);
            #pragma unroll
            for (int mi = 0; mi < 4; ++mi)
                #pragma unroll
                for (int ni = 0; ni < 4; ++ni)
                    acc[mi][ni] = __builtin_amdgcn_mfma_f32_16x16x32_bf16(bfv[kk][ni], af[mi], acc[mi][ni], 0, 0, 0);
        }
    }

    #pragma unroll
    for (int mi = 0; mi < 4; ++mi) {
        int row = bm + wm + mi * 16 + l16;
        #pragma unroll
        for (int ni = 0; ni < 4; ++ni) {
            int col0 = bn + wn + ni * 16 + quad * 4;
            float4 b4 = *reinterpret_cast<const float4*>(&bias[col0]);
            float v0 = (acc[mi][ni][0] + b4.x) * scale;
            float v1 = (acc[mi][ni][1] + b4.y) * scale;
            float v2 = (acc[mi][ni][2] + b4.z) * scale;
            float v3 = (acc[mi][ni][3] + b4.w) * scale;
            if (mode == 0) {
                ushort4 o4; o4.x = f2bf(v0); o4.y = f2bf(v1); o4.z = f2bf(v2); o4.w = f2bf(v3);
                *reinterpret_cast<ushort4*>(&reinterpret_cast<unsigned short*>(out)[(size_t)row * N + col0]) = o4;
            } else {
                float4 o4; o4.x = v0; o4.y = v1; o4.z = v2; o4.w = v3;
                *reinterpret_cast<float4*>(&reinterpret_cast<float*>(out)[(size_t)row * N + col0]) = o4;
            }
        }
    }
}

// ---------------- weight fold: W_eff^T[z] = wT[z] @ WcB[:, z*1024 +: 1024]  (bf16 out, B-direct) ----------------
__global__ __launch_bounds__(256) void k_foldw(
    const unsigned short* __restrict__ wT3,
    const unsigned short* __restrict__ WcB,
    unsigned short* __restrict__ Weff)
{
    __shared__ unsigned short As[16384];
    int z = blockIdx.z;
    const unsigned short* A  = wT3 + (size_t)z * 1024 * 1024;
    const unsigned short* Bt = WcB + z * 1024;
    unsigned short* out = Weff + (size_t)z * 1024 * 1024;
    float scale = (z == 0) ? 0.1803368801f : 1.f;

    int tid  = threadIdx.x;
    int lane = tid & 63, wv = tid >> 6;
    int quad = lane >> 4, l16 = lane & 15;
    int bm = blockIdx.y * 128, bn = blockIdx.x * 128;
    int wm = (wv >> 1) * 64,  wn = (wv & 1) * 64;

    f32x4 acc[4][4] = {};
    int srow = tid >> 2, scol = (tid & 3) * 8;
    const unsigned short* brow = &Bt[(size_t)(bn + wn + l16) * 3072 + quad * 8];

    #pragma unroll
    for (int kk = 0; kk < 2; ++kk)
        #pragma unroll
        for (int s = 0; s < 2; ++s) {
            int row = s * 64 + srow;
            gl_lds16(&A[(size_t)(bm + row) * 1024 + kk * 32 + scol], &As[kk * 4096 + (s * 256 + wv * 64) * 8]);
        }

    for (int i = 0; i < 16; ++i) {
        int k0 = i << 6;
        int cur = (i & 1) * 8192;
        bf16x8 bfv[2][4];
        #pragma unroll
        for (int kk = 0; kk < 2; ++kk)
            #pragma unroll
            for (int ni = 0; ni < 4; ++ni)
                bfv[kk][ni] = *reinterpret_cast<const bf16x8*>(&brow[(size_t)ni * 16 * 3072 + k0 + kk * 32]);
        __syncthreads();
        if (i + 1 < 16) {
            int nxt = ((i + 1) & 1) * 8192;
            #pragma unroll
            for (int kk = 0; kk < 2; ++kk)
                #pragma unroll
                for (int s = 0; s < 2; ++s) {
                    int row = s * 64 + srow;
                    gl_lds16(&A[(size_t)(bm + row) * 1024 + k0 + 64 + kk * 32 + scol],
                             &As[nxt + kk * 4096 + (s * 256 + wv * 64) * 8]);
                }
        }
        #pragma unroll
        for (int kk = 0; kk < 2; ++kk) {
            bf16x8 af[4];
            #pragma unroll
            for (int mi = 0; mi < 4; ++mi)
                af[mi] = *reinterpret_cast<const bf16x8*>(&As[cur + kk * 4096 + (wm + mi * 16 + l16) * 32 + quad * 8]);
            #pragma unroll
            for (int mi = 0; mi < 4; ++mi)
                #pragma unroll
                for (int ni = 0; ni < 4; ++ni)
                    acc[mi][ni] = __builtin_amdgcn_mfma_f32_16x16x32_bf16(bfv[kk][ni], af[mi], acc[mi][ni], 0, 0, 0);
        }
    }

    #pragma unroll
    for (int mi = 0; mi < 4; ++mi) {
        int row = bm + wm + mi * 16 + l16;
        #pragma unroll
        for (int ni = 0; ni < 4; ++ni) {
            int col0 = bn + wn + ni * 16 + quad * 4;
            ushort4 o4;
            o4.x = f2bf(acc[mi][ni][0] * scale);
            o4.y = f2bf(acc[mi][ni][1] * scale);
            o4.z = f2bf(acc[mi][ni][2] * scale);
            o4.w = f2bf(acc[mi][ni][3] * scale);
            *reinterpret_cast<ushort4*>(&out[(size_t)row * 1024 + col0]) = o4;
        }
    }
}

// ---------------- bias fold: one wave per output, vectorized + shuffle reduce ----------------
__global__ __launch_bounds__(256) void k_foldb(
    const unsigned short* __restrict__ wT3, const float* __restrict__ bc,
    const float* __restrict__ qb, const float* __restrict__ kb,
    const float* __restrict__ vb, float* __restrict__ beff)
{
    int wv = threadIdx.x >> 6, lane = threadIdx.x & 63;
    int id = blockIdx.x * 4 + wv;   // grid 768 -> ids 0..3071
    int z = id >> 10, n = id & 1023;
    const unsigned short* row = wT3 + (size_t)z * 1024 * 1024 + (size_t)n * 1024;
    const float* bcz = bc + z * 1024;
    float s = 0.f;
    #pragma unroll
    for (int it = 0; it < 2; ++it) {
        int c0 = it * 512 + lane * 8;
        uint4 v = *reinterpret_cast<const uint4*>(&row[c0]);
        const unsigned short* pv = reinterpret_cast<const unsigned short*>(&v);
        float4 f0 = *reinterpret_cast<const float4*>(&bcz[c0]);
        float4 f1 = *reinterpret_cast<const float4*>(&bcz[c0 + 4]);
        s += f0.x * bf2f(pv[0]) + f0.y * bf2f(pv[1]) + f0.z * bf2f(pv[2]) + f0.w * bf2f(pv[3]);
        s += f1.x * bf2f(pv[4]) + f1.y * bf2f(pv[5]) + f1.z * bf2f(pv[6]) + f1.w * bf2f(pv[7]);
    }
    s += __shfl_xor(s, 1); s += __shfl_xor(s, 2); s += __shfl_xor(s, 4);
    s += __shfl_xor(s, 8); s += __shfl_xor(s, 16); s += __shfl_xor(s, 32);
    if (lane == 0) {
        const float* b2 = (z == 0) ? qb : (z == 1) ? kb : vb;
        float r = s + b2[n];
        if (z == 0) r *= 0.1803368801f;
        beff[id] = r;
    }
}

// ---------------- fused projections: x @ W_eff[z] + b_eff[z] -> gathered layouts ----------------
// K-loop: A staged (LDS dbuf, 1 barrier/iter), B (Weff, L2-resident) direct global->reg.
// z<2 swapped mfma(B,A) [t on lanes, d on regs]; z==2 normal [d on lanes, t on regs].
// Epilogue: stage full 128x128 tile in LDS (As dead), then branch regions copied out as
// fully-contiguous bulk writes (consecutive t -> consecutive idx => 16/8/4 KB contiguous per head).
__global__ __launch_bounds__(256) void k_gemm3(
    const unsigned short* __restrict__ A,      // xb [8192][1024]
    const unsigned short* __restrict__ Weff,   // [3][1024][1024]
    const float* __restrict__ beff,            // [3][1024]
    unsigned short* __restrict__ Qg, unsigned short* __restrict__ Kg,
    unsigned short* __restrict__ Vtg)
{
    __shared__ unsigned short smem[16896];     // As dbuf (16384) in loop; T[128][132] in epilogue
    unsigned short* As = smem;
    const int TS = 132;

    int tid  = threadIdx.x;
    int lane = tid & 63, wv = tid >> 6;
    int quad = lane >> 4, l16 = lane & 15;

    // XCD-aware chunked swizzle (nwg = 1536, % 8 == 0 -> bijective); grid dims known: (8,64,3)
    int nwg = gridDim.x * gridDim.y * gridDim.z;
    int lin = (blockIdx.z * gridDim.y + blockIdx.y) * gridDim.x + blockIdx.x;
    int swz = (lin & 7) * (nwg >> 3) + (lin >> 3);
    int bx  = swz & 7;
    int tmp = swz >> 3;
    int by  = tmp & 63;
    int z   = tmp >> 6;

    const unsigned short* Bt = Weff + (size_t)z * 1024 * 1024;
    const float* bias = beff + z * 1024;

    int bm = by * 128, bn = bx * 128;
    int wm = (wv >> 1) * 64,  wn = (wv & 1) * 64;

    f32x4 acc[4][4] = {};
    int srow = tid >> 2, scol = (tid & 3) * 8;
    const unsigned short* brow = &Bt[(size_t)(bn + wn + l16) * 1024 + quad * 8];

    #pragma unroll
    for (int kk = 0; kk < 2; ++kk)
        #pragma unroll
        for (int s = 0; s < 2; ++s) {
            int row = s * 64 + srow;
            gl_lds16(&A[(size_t)(bm + row) * 1024 + kk * 32 + scol], &As[kk * 4096 + (s * 256 + wv * 64) * 8]);
        }

    for (int i = 0; i < 16; ++i) {
        int k0 = i << 6;
        int cur = (i & 1) * 8192;
        bf16x8 bfv[2][4];
        #pragma unroll
        for (int kk = 0; kk < 2; ++kk)
            #pragma unroll
            for (int ni = 0; ni < 4; ++ni)
                bfv[kk][ni] = *reinterpret_cast<const bf16x8*>(&brow[(size_t)ni * 16 * 1024 + k0 + kk * 32]);
        __syncthreads();
        if (i + 1 < 16) {
            int nxt = ((i + 1) & 1) * 8192;
            #pragma unroll
            for (int kk = 0; kk < 2; ++kk)
                #pragma unroll
                for (int s = 0; s < 2; ++s) {
                    int row = s * 64 + srow;
                    gl_lds16(&A[(size_t)(bm + row) * 1024 + k0 + 64 + kk * 32 + scol],
                             &As[nxt + kk * 4096 + (s * 256 + wv * 64) * 8]);
                }
        }
        #pragma unroll
        for (int kk = 0; kk < 2; ++kk) {
            bf16x8 af[4];
            #pragma unroll
            for (int mi = 0; mi < 4; ++mi)
                af[mi] = *reinterpret_cast<const bf16x8*>(&As[cur + kk * 4096 + (wm + mi * 16 + l16) * 32 + quad * 8]);
            if (z < 2) {
                #pragma unroll
                for (int mi = 0; mi < 4; ++mi)
                    #pragma unroll
                    for (int ni = 0; ni < 4; ++ni)
                        acc[mi][ni] = __builtin_amdgcn_mfma_f32_16x16x32_bf16(bfv[kk][ni], af[mi], acc[mi][ni], 0, 0, 0);
            } else {
                #pragma unroll
                for (int mi = 0; mi < 4; ++mi)
                    #pragma unroll
                    for (int ni = 0; ni < 4; ++ni)
                        acc[mi][ni] = __builtin_amdgcn_mfma_f32_16x16x32_bf16(af[mi], bfv[kk][ni], acc[mi][ni], 0, 0, 0);
            }
        }
    }
    __syncthreads();   // all waves done reading As before T overwrites it

    unsigned short* T = smem;
    int b  = bm >> 12, t0 = bm & 4095;
    int h0 = bn >> 6;
    int slot0 = t0 >> 9;
    int slot1 = 8 + (t0 >> 10);
    int slot2 = 12 + (t0 >> 11);

    if (z < 2) {
        unsigned short* dst = (z == 0) ? Qg : Kg;
        // stage [t][d]: t on l16, d on regs (4 consecutive per quad)
        #pragma unroll
        for (int mi = 0; mi < 4; ++mi) {
            int tl = wm + mi * 16 + l16;
            #pragma unroll
            for (int ni = 0; ni < 4; ++ni) {
                int dl0 = wn + ni * 16 + quad * 4;
                float4 b4 = *reinterpret_cast<const float4*>(&bias[bn + dl0]);
                ushort4 o4;
                o4.x = f2bf(acc[mi][ni][0] + b4.x);
                o4.y = f2bf(acc[mi][ni][1] + b4.y);
                o4.z = f2bf(acc[mi][ni][2] + b4.z);
                o4.w = f2bf(acc[mi][ni][3] + b4.w);
                *reinterpret_cast<ushort4*>(&T[tl * TS + dl0]) = o4;
            }
        }
        __syncthreads();
        // branch 0: per head 128 t x 64 d -> contiguous 16 KB
        #pragma unroll
        for (int rep = 0; rep < 8; ++rep) {
            int c = rep * 256 + tid;
            int h = c >> 10, rr = c & 1023;
            int tl = rr >> 3, dseg = (rr & 7) * 8;
            int bh = b * 16 + h0 + h;
            size_t base = ((size_t)(slot0 * 32 + bh) * 512 + (t0 & 511) + tl) * 64;
            *reinterpret_cast<uint4*>(&dst[base + dseg]) =
                *reinterpret_cast<const uint4*>(&T[tl * TS + h * 64 + dseg]);
        }
        // branch 1: parity-matching t -> contiguous 8 KB per head
        #pragma unroll
        for (int rep = 0; rep < 4; ++rep) {
            int c = rep * 256 + tid;
            int h = c >> 9, rr = c & 511;
            int i = rr >> 3, dseg = (rr & 7) * 8;
            int hh = h0 + h;
            int bh = b * 16 + hh;
            int tl = 2 * i + (hh & 1);
            size_t base = ((size_t)(slot1 * 32 + bh) * 512 + ((t0 & 1023) >> 1) + i) * 64;
            *reinterpret_cast<uint4*>(&dst[base + dseg]) =
                *reinterpret_cast<const uint4*>(&T[tl * TS + h * 64 + dseg]);
        }
        // branch 2: mod-4-matching t -> contiguous 4 KB per head
        #pragma unroll
        for (int rep = 0; rep < 2; ++rep) {
            int c = rep * 256 + tid;
            int h = c >> 8, rr = c & 255;
            int i = rr >> 3, dseg = (rr & 7) * 8;
            int hh = h0 + h;
            int bh = b * 16 + hh;
            int tl = 4 * i + (hh & 3);
            size_t base = ((size_t)(slot2 * 32 + bh) * 512 + ((t0 & 2047) >> 2) + i) * 64;
            *reinterpret_cast<uint4*>(&dst[base + dseg]) =
                *reinterpret_cast<const uint4*>(&T[tl * TS + h * 64 + dseg]);
        }
    } else {
        // stage transposed [d][t]: d on l16, t on regs (4 consecutive per quad)
        #pragma unroll
        for (int ni = 0; ni < 4; ++ni) {
            int dl = wn + ni * 16 + l16;
            float bsv = bias[bn + dl];
            #pragma unroll
            for (int mi = 0; mi < 4; ++mi) {
                int tl0 = wm + mi * 16 + quad * 4;
                ushort4 o4;
                o4.x = f2bf(acc[mi][ni][0] + bsv);
                o4.y = f2bf(acc[mi][ni][1] + bsv);
                o4.z = f2bf(acc[mi][ni][2] + bsv);
                o4.w = f2bf(acc[mi][ni][3] + bsv);
                *reinterpret_cast<ushort4*>(&T[dl * TS + tl0]) = o4;
            }
        }
        __syncthreads();
        // branch 0: per (head,d) 128 t -> 256 B contiguous
        #pragma unroll
        for (int rep = 0; rep < 8; ++rep) {
            int c = rep * 256 + tid;
            int h = c >> 10, rr = c & 1023;
            int d = rr >> 4, seg = (rr & 15) * 8;
            int bh = b * 16 + h0 + h;
            size_t base = ((size_t)(slot0 * 32 + bh) * 64 + d) * 512 + (t0 & 511);
            *reinterpret_cast<uint4*>(&Vtg[base + seg]) =
                *reinterpret_cast<const uint4*>(&T[(h * 64 + d) * TS + seg]);
        }
        // branch 1: stride-2 LDS gather, contiguous 128 B per (head,d)
        #pragma unroll
        for (int rep = 0; rep < 4; ++rep) {
            int c = rep * 256 + tid;
            int h = c >> 9, rr = c & 511;
            int d = rr >> 3, seg = rr & 7;
            int hh = h0 + h;
            int bh = b * 16 + hh;
            int p = hh & 1;
            const unsigned short* srw = &T[(h * 64 + d) * TS];
            unsigned short buf[8];
            #pragma unroll
            for (int j = 0; j < 8; ++j) buf[j] = srw[p + 2 * (seg * 8 + j)];
            size_t base = ((size_t)(slot1 * 32 + bh) * 64 + d) * 512 + ((t0 & 1023) >> 1);
            *reinterpret_cast<uint4*>(&Vtg[base + seg * 8]) = *reinterpret_cast<const uint4*>(buf);
        }
        // branch 2: stride-4 LDS gather, contiguous 64 B per (head,d)
        #pragma unroll
        for (int rep = 0; rep < 2; ++rep) {
            int c = rep * 256 + tid;
            int h = c >> 8, rr = c & 255;
            int d = rr >> 2, seg = rr & 3;
            int hh = h0 + h;
            int bh = b * 16 + hh;
            int p = hh & 3;
            const unsigned short* srw = &T[(h * 64 + d) * TS];
            unsigned short buf[8];
            #pragma unroll
            for (int j = 0; j < 8; ++j) buf[j] = srw[p + 4 * (seg * 8 + j)];
            size_t base = ((size_t)(slot2 * 32 + bh) * 64 + d) * 512 + ((t0 & 2047) >> 2);
            *reinterpret_cast<uint4*>(&Vtg[base + seg * 8]) = *reinterpret_cast<const uint4*>(buf);
        }
    }
}

// ---------------- dilated attention: swapped QK^T (S^T) + permuted-K staging => P stays in-register ----------------
__global__ __launch_bounds__(256, 3) void k_attn(
    const unsigned short* __restrict__ Qg,
    const unsigned short* __restrict__ Kg,
    const unsigned short* __restrict__ Vtg,
    unsigned short* __restrict__ Og,
    float* __restrict__ Lg)
{
    __shared__ unsigned short Ks[2][64 * 72];
    __shared__ unsigned short Vs[2][64 * 72];      // [d][kcol] (pre-transposed in global)

    int tid  = threadIdx.x;
    int lane = tid & 63, wv = tid >> 6;
    int quad = lane >> 4, l16 = lane & 15;
    int q8   = quad << 3;
    int pq = blockIdx.x, ys = blockIdx.y, bh = blockIdx.z;
    int jt_end = 2 * (3 - pq) + 1;    // 7 (pair 0,3) or 5 (pair 1,2)
    size_t sb = (size_t)(ys * 32 + bh) * (512 * 64);
    const unsigned short* qp = Qg + sb;
    const unsigned short* kp = Kg + sb;
    const unsigned short* vp = Vtg + sb;
    unsigned short* op = Og + sb;
    float* lp = Lg + (size_t)(ys * 32 + bh) * 512;

    int rw[2] = { pq * 128 + wv * 32, (3 - pq) * 128 + wv * 32 };

    // staging geometry: thread covers rows {srow, srow+32} cols sc8..sc8+7
    int srow = tid >> 3, sc8 = (tid & 7) * 8;
    // K-row permutation (bijective on 0..31): makes S^T output k-slots land in natural PV order.
    int prow = ((srow >> 2) & 1) * 16 + ((srow >> 3) & 3) * 4 + (srow & 3);
    uint4 kr[2], vr[2];
    {   // preload jt = 0
        #pragma unroll
        for (int s = 0; s < 2; ++s) {
            int row = s * 32 + srow;
            kr[s] = *reinterpret_cast<const uint4*>(&kp[(size_t)row * 64 + sc8]);
            vr[s] = *reinterpret_cast<const uint4*>(&vp[(size_t)row * 512 + sc8]);
        }
    }

    bf16x8 qf[2][2][2];
    #pragma unroll
    for (int qi = 0; qi < 2; ++qi)
        #pragma unroll
        for (int m16 = 0; m16 < 2; ++m16)
            #pragma unroll
            for (int kk = 0; kk < 2; ++kk)
                qf[qi][m16][kk] = *reinterpret_cast<const bf16x8*>(
                    &qp[(size_t)(rw[qi] + m16 * 16 + l16) * 64 + kk * 32 + quad * 8]);

    f32x4 acc[2][2][4] = {};
    float l4[2][2] = {};

    for (int jt = 0; jt <= jt_end; ++jt) {
        unsigned short* Kb = &Ks[jt & 1][0];
        unsigned short* Vb = &Vs[jt & 1][0];
        #pragma unroll
        for (int s = 0; s < 2; ++s) {
            *reinterpret_cast<uint4*>(&Kb[(s * 32 + prow) * 72 + sc8]) = kr[s];
            *reinterpret_cast<uint4*>(&Vb[(s * 32 + srow) * 72 + sc8]) = vr[s];
        }
        if (jt < jt_end) {   // prefetch next tile into regs; loads fly during compute below
            #pragma unroll
            for (int s = 0; s < 2; ++s) {
                int row = s * 32 + srow;
                kr[s] = *reinterpret_cast<const uint4*>(&kp[(size_t)((jt + 1) * 64 + row) * 64 + sc8]);
                vr[s] = *reinterpret_cast<const uint4*>(&vp[(size_t)row * 512 + (jt + 1) * 64 + sc8]);
            }
        }
        __syncthreads();     // dbuf: single barrier per jt

        #pragma unroll
        for (int qi = 0; qi < 2; ++qi) {
            #pragma unroll
            for (int m16 = 0; m16 < 2; ++m16) {
                int rowbase = rw[qi] + m16 * 16;
                if (jt * 64 > rowbase + 15) continue;

                // S^T = mfma(K, Q): lane holds S[q=l16][k = jt*64 + (nt>>1)*32 + quad*8 + (nt&1)*4 + ri]
                f32x4 sacc[4];
                __builtin_amdgcn_s_setprio(1);
                #pragma unroll
                for (int nt = 0; nt < 4; ++nt) {
                    bf16x8 b0 = *reinterpret_cast<const bf16x8*>(&Kb[(nt * 16 + l16) * 72 + quad * 8]);
                    bf16x8 b1 = *reinterpret_cast<const bf16x8*>(&Kb[(nt * 16 + l16) * 72 + 32 + quad * 8]);
                    f32x4 s4 = {};
                    s4 = __builtin_amdgcn_mfma_f32_16x16x32_bf16(b0, qf[qi][m16][0], s4, 0, 0, 0);
                    s4 = __builtin_amdgcn_mfma_f32_16x16x32_bf16(b1, qf[qi][m16][1], s4, 0, 0, 0);
                    sacc[nt] = s4;
                }
                __builtin_amdgcn_s_setprio(0);

                if (jt * 64 + 63 > rowbase) {
                    int qrow = rowbase + l16;
                    #pragma unroll
                    for (int nt = 0; nt < 4; ++nt)
                        #pragma unroll
                        for (int ri = 0; ri < 4; ++ri) {
                            int kj = jt * 64 + (nt >> 1) * 32 + (nt & 1) * 4 + q8 + ri;
                            if (kj > qrow) sacc[nt][ri] = -1e30f;
                        }
                }
                float ls = 0.f;
                #pragma unroll
                for (int nt = 0; nt < 4; ++nt)
                    #pragma unroll
                    for (int ri = 0; ri < 4; ++ri) {
                        float p = __builtin_amdgcn_exp2f(sacc[nt][ri]);
                        sacc[nt][ri] = p;
                        ls += p;
                    }
                l4[qi][m16] += ls;

                // P -> bf16 A-fragments: fully lane-local, naturally ordered (thanks to K permute)
                union { unsigned int u[4]; bf16x8 v; } p0u, p1u;
                asm("v_cvt_pk_bf16_f32 %0, %1, %2" : "=v"(p0u.u[0]) : "v"(sacc[0][0]), "v"(sacc[0][1]));
                asm("v_cvt_pk_bf16_f32 %0, %1, %2" : "=v"(p0u.u[1]) : "v"(sacc[0][2]), "v"(sacc[0][3]));
                asm("v_cvt_pk_bf16_f32 %0, %1, %2" : "=v"(p0u.u[2]) : "v"(sacc[1][0]), "v"(sacc[1][1]));
                asm("v_cvt_pk_bf16_f32 %0, %1, %2" : "=v"(p0u.u[3]) : "v"(sacc[1][2]), "v"(sacc[1][3]));
                asm("v_cvt_pk_bf16_f32 %0, %1, %2" : "=v"(p1u.u[0]) : "v"(sacc[2][0]), "v"(sacc[2][1]));
                asm("v_cvt_pk_bf16_f32 %0, %1, %2" : "=v"(p1u.u[1]) : "v"(sacc[2][2]), "v"(sacc[2][3]));
                asm("v_cvt_pk_bf16_f32 %0, %1, %2" : "=v"(p1u.u[2]) : "v"(sacc[3][0]), "v"(sacc[3][1]));
                asm("v_cvt_pk_bf16_f32 %0, %1, %2" : "=v"(p1u.u[3]) : "v"(sacc[3][2]), "v"(sacc[3][3]));

                __builtin_amdgcn_s_setprio(1);
                #pragma unroll
                for (int dt = 0; dt < 4; ++dt) {
                    bf16x8 v0 = *reinterpret_cast<const bf16x8*>(&Vb[(dt * 16 + l16) * 72 + quad * 8]);
                    bf16x8 v1 = *reinterpret_cast<const bf16x8*>(&Vb[(dt * 16 + l16) * 72 + 32 + quad * 8]);
                    f32x4 a4 = acc[qi][m16][dt];
                    a4 = __builtin_amdgcn_mfma_f32_16x16x32_bf16(p0u.v, v0, a4, 0, 0, 0);
                    a4 = __builtin_amdgcn_mfma_f32_16x16x32_bf16(p1u.v, v1, a4, 0, 0, 0);
                    acc[qi][m16][dt] = a4;
                }
                __builtin_amdgcn_s_setprio(0);
            }
        }
    }

    #pragma unroll
    for (int qi = 0; qi < 2; ++qi)
        #pragma unroll
        for (int m16 = 0; m16 < 2; ++m16) {
            int rowb = rw[qi] + m16 * 16;
            float L = l4[qi][m16];
            L += __shfl_xor(L, 16);
            L += __shfl_xor(L, 32);       // full row sum for q-row rowb + l16 (dup across quads)
            float inv[4];
            #pragma unroll
            for (int ri = 0; ri < 4; ++ri)
                inv[ri] = 1.f / __shfl(L, quad * 4 + ri);
            #pragma unroll
            for (int dt = 0; dt < 4; ++dt)
                #pragma unroll
                for (int ri = 0; ri < 4; ++ri) {
                    int row = rowb + quad * 4 + ri;
                    op[(size_t)row * 64 + dt * 16 + l16] = f2bf(acc[qi][m16][dt][ri] * inv[ri]);
                }
            if (lane < 16)
                lp[rowb + l16] = __logf(L);
        }
}

// ---------------- combine branches via LSE weights ----------------
__global__ void k_combine(const unsigned short* __restrict__ Og,
                          const float* __restrict__ Lg,
                          unsigned short* __restrict__ yb)
{
    int g   = blockIdx.x * blockDim.x + threadIdx.x;
    int row = g >> 3;
    int d0  = (g & 7) * 8;
    int bh = row >> 12, t = row & 4095;
    int b = bh >> 4, h = bh & 15;

    int slot0 = t >> 9,         idx0 = t & 511;
    int slot1 = 8 + (t >> 10),  idx1 = (t & 1023) >> 1;
    int slot2 = 12 + (t >> 11), idx2 = (t & 2047) >> 2;
    size_t r0 = (size_t)(slot0 * 32 + bh) * 512 + idx0;
    size_t r1 = (size_t)(slot1 * 32 + bh) * 512 + idx1;
    size_t r2 = (size_t)(slot2 * 32 + bh) * 512 + idx2;
    bool c1 = ((t ^ h) & 1) == 0;
    bool c2 = ((t ^ h) & 3) == 0;

    float L0 = Lg[r0];
    float L1 = c1 ? Lg[r1] : -1e30f;
    float L2 = c2 ? Lg[r2] : -1e30f;
    float m  = fmaxf(L0, fmaxf(L1, L2));
    float w0 = __expf(L0 - m), w1 = __expf(L1 - m), w2 = __expf(L2 - m);
    float inv = 1.f / (w0 + w1 + w2);

    uint4 v0 = *reinterpret_cast<const uint4*>(&Og[r0 * 64 + d0]);
    uint4 v1 = *reinterpret_cast<const uint4*>(&Og[r1 * 64 + d0]);
    uint4 v2 = *reinterpret_cast<const uint4*>(&Og[r2 * 64 + d0]);
    const unsigned short* p0 = reinterpret_cast<const unsigned short*>(&v0);
    const unsigned short* p1 = reinterpret_cast<const unsigned short*>(&v1);
    const unsigned short* p2 = reinterpret_cast<const unsigned short*>(&v2);
    unsigned short o[8];
    #pragma unroll
    for (int u = 0; u < 8; ++u)
        o[u] = f2bf((w0 * bf2f(p0[u]) + w1 * bf2f(p1[u]) + w2 * bf2f(p2[u])) * inv);
    size_t yidx = (((size_t)b * 4096 + t) * 1024) + (size_t)h * 64 + d0;
    *reinterpret_cast<uint4*>(&yb[yidx]) = *reinterpret_cast<const uint4*>(o);
}

extern "C" void kernel_launch(void* const* d_in, const int* in_sizes, int n_in,
                              void* d_out, int out_size, void* d_ws, size_t ws_size,
                              hipStream_t stream)
{
    const float* x        = (const float*)d_in[0];
    const float* c_attn_w = (const float*)d_in[1];
    const float* c_attn_b = (const float*)d_in[2];
    const float* q_w      = (const float*)d_in[3];
    const float* q_b      = (const float*)d_in[4];
    const float* k_w      = (const float*)d_in[5];
    const float* k_b      = (const float*)d_in[6];
    const float* v_w      = (const float*)d_in[7];
    const float* v_b      = (const float*)d_in[8];
    const float* o_w      = (const float*)d_in[9];
    const float* o_b      = (const float*)d_in[10];

    char* ws = (char*)d_ws;
    size_t off = 0;
    auto alloc = [&](size_t bytes) -> char* {
        char* p = ws + off; off += (bytes + 255) & ~(size_t)255; return p;
    };
    const size_t GSZ = 14ull * 32 * 512 * 64;
    unsigned short* xb    = (unsigned short*)alloc(8192ull * 1024 * 2);
    unsigned short* WcB   = (unsigned short*)alloc(1024ull * 3072 * 2);   // c_attn_w bf16, untransposed
    unsigned short* wqT   = (unsigned short*)alloc(1024ull * 1024 * 2);   // q/k/v contiguous
    unsigned short* wkT   = (unsigned short*)alloc(1024ull * 1024 * 2);
    unsigned short* wvT   = (unsigned short*)alloc(1024ull * 1024 * 2);
    unsigned short* woT   = (unsigned short*)alloc(1024ull * 1024 * 2);
    unsigned short* Weff  = (unsigned short*)alloc(3ull * 1024 * 1024 * 2);
    float*          beff  = (float*)alloc(3ull * 1024 * 4);
    unsigned short* Qg    = (unsigned short*)alloc(GSZ * 2);
    unsigned short* Kg    = (unsigned short*)alloc(GSZ * 2);
    unsigned short* Vtg   = (unsigned short*)alloc(GSZ * 2);
    unsigned short* Og    = (unsigned short*)alloc(GSZ * 2);
    float*          Lg    = (float*)alloc(14ull * 32 * 512 * 4);
    unsigned short* yb    = xb;   // alias: xb dead after k_gemm3
    (void)wkT; (void)wvT;

    // 1. fused casts (x -> xb, c_attn_w -> WcB) in one dispatch
    k_cast2<<<8192 + 3072, 256, 0, stream>>>(x, xb, c_attn_w, WcB);
    // 2. transpose-cast q/k/v/o weights (one dispatch)
    k_transpose4<<<dim3(32, 32, 4), dim3(32, 8), 0, stream>>>(q_w, k_w, v_w, o_w, wqT, wkT, wvT, woT);
    // 3. weight/bias folding
    k_foldw<<<dim3(8, 8, 3), 256, 0, stream>>>(wqT, WcB, Weff);
    k_foldb<<<768, 256, 0, stream>>>(wqT, c_attn_b, q_b, k_b, v_b, beff);
    // 4. fused projections: x -> gathered Q/K/V^T (A-dbuf 1-barrier, B-direct, XCD swizzle)
    k_gemm3<<<dim3(8, 64, 3), 256, 0, stream>>>(xb, Weff, beff, Qg, Kg, Vtg);
    // 5. attention (swapped-QK in-register P, dbuf K/V, single barrier per tile)
    k_attn<<<dim3(2, 14, 32), 256, 0, stream>>>(Qg, Kg, Vtg, Og, Lg);
    // 6. combine -> y
    k_combine<<<4096, 256, 0, stream>>>(Og, Lg, yb);
    // 7. out = y @ o_w + o_b (fp32, A-dbuf 1-barrier, B-direct)
    k_gemm<<<dim3(8, 64), 256, 0, stream>>>(yb, 1024, woT, 1024, o_b, d_out, 8192, 1024, 1024, 2, 1.f);
}

// Round 6
// 331.517 us; speedup vs baseline: 1.1281x; 1.1281x over previous
//
#include <hip/hip_runtime.h>
#include <hip/hip_bf16.h>

typedef __bf16 bf16x8 __attribute__((ext_vector_type(8)));
typedef float  f32x4  __attribute__((ext_vector_type(4)));

__device__ __forceinline__ unsigned short f2bf(float f) {
    union { float f; unsigned int u; } v; v.f = f;
    return (unsigned short)((v.u + 0x8000u) >> 16);   // round-half-up: 2 VALU
}
__device__ __forceinline__ float bf2f(unsigned short h) {
    union { unsigned int u; float f; } v; v.u = ((unsigned int)h) << 16;
    return v.f;
}

typedef __attribute__((address_space(3))) unsigned int lds_u32_t;
typedef const __attribute__((address_space(1))) unsigned int glb_u32_t;
__device__ __forceinline__ void gl_lds16(const void* g, void* l) {
    __builtin_amdgcn_global_load_lds((glb_u32_t*)g, (lds_u32_t*)l, 16, 0, 0);
}

// ---------------- fused casts fp32 -> bf16 (x and c_attn_w in one dispatch) ----------------
__global__ void k_cast2(const float* __restrict__ a, unsigned short* __restrict__ oa,
                        const float* __restrict__ b, unsigned short* __restrict__ ob) {
    int blk = blockIdx.x;
    const float* in;
    unsigned short* out;
    int base;
    if (blk < 8192) { in = a; out = oa; base = blk * 1024; }
    else            { in = b; out = ob; base = (blk - 8192) * 1024; }
    int i = base + threadIdx.x * 4;
    float4 v = *reinterpret_cast<const float4*>(in + i);
    ushort4 o;
    o.x = f2bf(v.x); o.y = f2bf(v.y); o.z = f2bf(v.z); o.w = f2bf(v.w);
    *reinterpret_cast<ushort4*>(out + i) = o;
}

// ---------------- 4x transpose+cast 1024x1024: [K][N] f32 -> [N][K] bf16 ----------------
__global__ void k_transpose4(const float* __restrict__ s0, const float* __restrict__ s1,
                             const float* __restrict__ s2, const float* __restrict__ s3,
                             unsigned short* __restrict__ d0, unsigned short* __restrict__ d1,
                             unsigned short* __restrict__ d2, unsigned short* __restrict__ d3) {
    __shared__ float tile[32][33];
    int z = blockIdx.z;
    const float* in = (z == 0) ? s0 : (z == 1) ? s1 : (z == 2) ? s2 : s3;
    unsigned short* out = (z == 0) ? d0 : (z == 1) ? d1 : (z == 2) ? d2 : d3;
    int n0 = blockIdx.x * 32, k0 = blockIdx.y * 32;
    int tx = threadIdx.x, ty = threadIdx.y; // block (32,8)
    #pragma unroll
    for (int i = 0; i < 4; ++i)
        tile[ty + i * 8][tx] = in[(size_t)(k0 + ty + i * 8) * 1024 + n0 + tx];
    __syncthreads();
    #pragma unroll
    for (int i = 0; i < 4; ++i)
        out[(size_t)(n0 + ty + i * 8) * 1024 + k0 + tx] = f2bf(tile[tx][ty + i * 8]);
}

// ---------------- bf16 MFMA GEMM: LDS double-buffer, prefetch AFTER the single barrier ----------------
// Swapped mfma(B,A): lane dim = A-row, reg dim = B-col -> 4 consecutive cols per lane -> vector stores.
// dbuf schedule: barrier(i) drains stage(i) issued one full compute phase ago (cheap drain);
// stage(i+1) issued right after the barrier into the other half (WAR-safe: 2-apart barriers).
// mode 0: out bf16 row-major [M,N];  mode 2: out fp32 row-major [M,N]
__global__ __launch_bounds__(256) void k_gemm(
    const unsigned short* __restrict__ A, int lda,
    const unsigned short* __restrict__ Bt, int ldb,
    const float* __restrict__ bias,
    void* __restrict__ out,
    int M, int N, int K, int mode, float scale)
{
    __shared__ unsigned short As[8192];   // [2 buf][128][32]
    __shared__ unsigned short Bs[8192];
    int tid  = threadIdx.x;
    int lane = tid & 63, wv = tid >> 6;
    int quad = lane >> 4, l16 = lane & 15;

    // XCD-aware chunked swizzle (bijective when nwg % 8 == 0)
    int nwg = gridDim.x * gridDim.y;
    int lin = blockIdx.y * gridDim.x + blockIdx.x;
    int bx = blockIdx.x, by = blockIdx.y;
    if ((nwg & 7) == 0) {
        int swz = (lin & 7) * (nwg >> 3) + (lin >> 3);
        bx = swz % gridDim.x;
        by = swz / gridDim.x;
    }
    int bm = by * 128, bn = bx * 128;
    int wm = (wv >> 1) * 64,  wn = (wv & 1) * 64;

    f32x4 acc[4][4] = {};
    int srow = tid >> 2, scol = (tid & 3) * 8;

    auto stage = [&](int k0, int buf) {
        #pragma unroll
        for (int s = 0; s < 2; ++s) {
            int row = s * 64 + srow;
            gl_lds16(&A[(size_t)(bm + row) * lda + k0 + scol], &As[buf * 4096 + (s * 256 + wv * 64) * 8]);
            gl_lds16(&Bt[(size_t)(bn + row) * ldb + k0 + scol], &Bs[buf * 4096 + (s * 256 + wv * 64) * 8]);
        }
    };
    stage(0, 0);

    int nk = K >> 5;
    for (int i = 0; i < nk; ++i) {
        __syncthreads();                       // drains stage(i) (issued one iter ago) + prev ds_reads
        if (i + 1 < nk) stage((i + 1) << 5, (i + 1) & 1);
        int cur = (i & 1) * 4096;
        bf16x8 af[4], bfv[4];
        #pragma unroll
        for (int mi = 0; mi < 4; ++mi)
            af[mi] = *reinterpret_cast<const bf16x8*>(&As[cur + (wm + mi * 16 + l16) * 32 + quad * 8]);
        #pragma unroll
        for (int ni = 0; ni < 4; ++ni)
            bfv[ni] = *reinterpret_cast<const bf16x8*>(&Bs[cur + (wn + ni * 16 + l16) * 32 + quad * 8]);
        #pragma unroll
        for (int mi = 0; mi < 4; ++mi)
            #pragma unroll
            for (int ni = 0; ni < 4; ++ni)
                acc[mi][ni] = __builtin_amdgcn_mfma_f32_16x16x32_bf16(bfv[ni], af[mi], acc[mi][ni], 0, 0, 0);
    }

    #pragma unroll
    for (int mi = 0; mi < 4; ++mi) {
        int row = bm + wm + mi * 16 + l16;
        #pragma unroll
        for (int ni = 0; ni < 4; ++ni) {
            int col0 = bn + wn + ni * 16 + quad * 4;
            float4 b4 = *reinterpret_cast<const float4*>(&bias[col0]);
            float v0 = (acc[mi][ni][0] + b4.x) * scale;
            float v1 = (acc[mi][ni][1] + b4.y) * scale;
            float v2 = (acc[mi][ni][2] + b4.z) * scale;
            float v3 = (acc[mi][ni][3] + b4.w) * scale;
            if (mode == 0) {
                ushort4 o4; o4.x = f2bf(v0); o4.y = f2bf(v1); o4.z = f2bf(v2); o4.w = f2bf(v3);
                *reinterpret_cast<ushort4*>(&reinterpret_cast<unsigned short*>(out)[(size_t)row * N + col0]) = o4;
            } else {
                float4 o4; o4.x = v0; o4.y = v1; o4.z = v2; o4.w = v3;
                *reinterpret_cast<float4*>(&reinterpret_cast<float*>(out)[(size_t)row * N + col0]) = o4;
            }
        }
    }
}

// ---------------- weight fold: W_eff^T[z] = wT[z] @ WcB[:, z*1024 +: 1024]  (bf16 out, dbuf) ----------------
__global__ __launch_bounds__(256) void k_foldw(
    const unsigned short* __restrict__ wT3,
    const unsigned short* __restrict__ WcB,
    unsigned short* __restrict__ Weff)
{
    __shared__ unsigned short As[8192];
    __shared__ unsigned short Bs[8192];
    int z = blockIdx.z;
    const unsigned short* A  = wT3 + (size_t)z * 1024 * 1024;
    const unsigned short* Bt = WcB + z * 1024;
    unsigned short* out = Weff + (size_t)z * 1024 * 1024;
    float scale = (z == 0) ? 0.1803368801f : 1.f;

    int tid  = threadIdx.x;
    int lane = tid & 63, wv = tid >> 6;
    int quad = lane >> 4, l16 = lane & 15;
    int bm = blockIdx.y * 128, bn = blockIdx.x * 128;
    int wm = (wv >> 1) * 64,  wn = (wv & 1) * 64;

    f32x4 acc[4][4] = {};
    int srow = tid >> 2, scol = (tid & 3) * 8;

    auto stage = [&](int k0, int buf) {
        #pragma unroll
        for (int s = 0; s < 2; ++s) {
            int row = s * 64 + srow;
            gl_lds16(&A[(size_t)(bm + row) * 1024 + k0 + scol], &As[buf * 4096 + (s * 256 + wv * 64) * 8]);
            gl_lds16(&Bt[(size_t)(bn + row) * 3072 + k0 + scol], &Bs[buf * 4096 + (s * 256 + wv * 64) * 8]);
        }
    };
    stage(0, 0);

    for (int i = 0; i < 32; ++i) {
        __syncthreads();
        if (i + 1 < 32) stage((i + 1) << 5, (i + 1) & 1);
        int cur = (i & 1) * 4096;
        bf16x8 af[4], bfv[4];
        #pragma unroll
        for (int mi = 0; mi < 4; ++mi)
            af[mi] = *reinterpret_cast<const bf16x8*>(&As[cur + (wm + mi * 16 + l16) * 32 + quad * 8]);
        #pragma unroll
        for (int ni = 0; ni < 4; ++ni)
            bfv[ni] = *reinterpret_cast<const bf16x8*>(&Bs[cur + (wn + ni * 16 + l16) * 32 + quad * 8]);
        #pragma unroll
        for (int mi = 0; mi < 4; ++mi)
            #pragma unroll
            for (int ni = 0; ni < 4; ++ni)
                acc[mi][ni] = __builtin_amdgcn_mfma_f32_16x16x32_bf16(bfv[ni], af[mi], acc[mi][ni], 0, 0, 0);
    }

    #pragma unroll
    for (int mi = 0; mi < 4; ++mi) {
        int row = bm + wm + mi * 16 + l16;
        #pragma unroll
        for (int ni = 0; ni < 4; ++ni) {
            int col0 = bn + wn + ni * 16 + quad * 4;
            ushort4 o4;
            o4.x = f2bf(acc[mi][ni][0] * scale);
            o4.y = f2bf(acc[mi][ni][1] * scale);
            o4.z = f2bf(acc[mi][ni][2] * scale);
            o4.w = f2bf(acc[mi][ni][3] * scale);
            *reinterpret_cast<ushort4*>(&out[(size_t)row * 1024 + col0]) = o4;
        }
    }
}

// ---------------- bias fold: one wave per output, vectorized + shuffle reduce ----------------
__global__ __launch_bounds__(256) void k_foldb(
    const unsigned short* __restrict__ wT3, const float* __restrict__ bc,
    const float* __restrict__ qb, const float* __restrict__ kb,
    const float* __restrict__ vb, float* __restrict__ beff)
{
    int wv = threadIdx.x >> 6, lane = threadIdx.x & 63;
    int id = blockIdx.x * 4 + wv;   // grid 768 -> ids 0..3071
    int z = id >> 10, n = id & 1023;
    const unsigned short* row = wT3 + (size_t)z * 1024 * 1024 + (size_t)n * 1024;
    const float* bcz = bc + z * 1024;
    float s = 0.f;
    #pragma unroll
    for (int it = 0; it < 2; ++it) {
        int c0 = it * 512 + lane * 8;
        uint4 v = *reinterpret_cast<const uint4*>(&row[c0]);
        const unsigned short* pv = reinterpret_cast<const unsigned short*>(&v);
        float4 f0 = *reinterpret_cast<const float4*>(&bcz[c0]);
        float4 f1 = *reinterpret_cast<const float4*>(&bcz[c0 + 4]);
        s += f0.x * bf2f(pv[0]) + f0.y * bf2f(pv[1]) + f0.z * bf2f(pv[2]) + f0.w * bf2f(pv[3]);
        s += f1.x * bf2f(pv[4]) + f1.y * bf2f(pv[5]) + f1.z * bf2f(pv[6]) + f1.w * bf2f(pv[7]);
    }
    s += __shfl_xor(s, 1); s += __shfl_xor(s, 2); s += __shfl_xor(s, 4);
    s += __shfl_xor(s, 8); s += __shfl_xor(s, 16); s += __shfl_xor(s, 32);
    if (lane == 0) {
        const float* b2 = (z == 0) ? qb : (z == 1) ? kb : vb;
        float r = s + b2[n];
        if (z == 0) r *= 0.1803368801f;
        beff[id] = r;
    }
}

// ---------------- fused projections: x @ W_eff[z] + b_eff[z] -> gathered layouts ----------------
// K-loop: LDS dbuf, prefetch-after-barrier (1 barrier/iter, cheap drains).
// z<2 swapped mfma(B,A) [t on lanes, d on regs]; z==2 normal [d on lanes, t on regs].
// Epilogue: stage full 128x128 tile in LDS (As/Bs dead), then branch regions copied out as
// fully-contiguous bulk writes (consecutive t -> consecutive idx => 16/8/4 KB contiguous per head).
__global__ __launch_bounds__(256) void k_gemm3(
    const unsigned short* __restrict__ A,      // xb [8192][1024]
    const unsigned short* __restrict__ Weff,   // [3][1024][1024]
    const float* __restrict__ beff,            // [3][1024]
    unsigned short* __restrict__ Qg, unsigned short* __restrict__ Kg,
    unsigned short* __restrict__ Vtg)
{
    __shared__ unsigned short smem[16896];     // As dbuf(8192)+Bs dbuf(8192) in loop; T[128][132] epilogue
    unsigned short* As = smem;
    unsigned short* Bs = smem + 8192;
    const int TS = 132;

    int tid  = threadIdx.x;
    int lane = tid & 63, wv = tid >> 6;
    int quad = lane >> 4, l16 = lane & 15;

    // XCD-aware chunked swizzle (nwg = 1536, % 8 == 0 -> bijective); grid dims known: (8,64,3)
    int nwg = gridDim.x * gridDim.y * gridDim.z;
    int lin = (blockIdx.z * gridDim.y + blockIdx.y) * gridDim.x + blockIdx.x;
    int swz = (lin & 7) * (nwg >> 3) + (lin >> 3);
    int bx  = swz & 7;
    int tmp = swz >> 3;
    int by  = tmp & 63;
    int z   = tmp >> 6;

    const unsigned short* Bt = Weff + (size_t)z * 1024 * 1024;
    const float* bias = beff + z * 1024;

    int bm = by * 128, bn = bx * 128;
    int wm = (wv >> 1) * 64,  wn = (wv & 1) * 64;

    f32x4 acc[4][4] = {};
    int srow = tid >> 2, scol = (tid & 3) * 8;

    auto stage = [&](int k0, int buf) {
        #pragma unroll
        for (int s = 0; s < 2; ++s) {
            int row = s * 64 + srow;
            gl_lds16(&A[(size_t)(bm + row) * 1024 + k0 + scol], &As[buf * 4096 + (s * 256 + wv * 64) * 8]);
            gl_lds16(&Bt[(size_t)(bn + row) * 1024 + k0 + scol], &Bs[buf * 4096 + (s * 256 + wv * 64) * 8]);
        }
    };
    stage(0, 0);

    for (int i = 0; i < 32; ++i) {
        __syncthreads();
        if (i + 1 < 32) stage((i + 1) << 5, (i + 1) & 1);
        int cur = (i & 1) * 4096;
        bf16x8 af[4], bfv[4];
        #pragma unroll
        for (int mi = 0; mi < 4; ++mi)
            af[mi] = *reinterpret_cast<const bf16x8*>(&As[cur + (wm + mi * 16 + l16) * 32 + quad * 8]);
        #pragma unroll
        for (int ni = 0; ni < 4; ++ni)
            bfv[ni] = *reinterpret_cast<const bf16x8*>(&Bs[cur + (wn + ni * 16 + l16) * 32 + quad * 8]);
        if (z < 2) {
            #pragma unroll
            for (int mi = 0; mi < 4; ++mi)
                #pragma unroll
                for (int ni = 0; ni < 4; ++ni)
                    acc[mi][ni] = __builtin_amdgcn_mfma_f32_16x16x32_bf16(bfv[ni], af[mi], acc[mi][ni], 0, 0, 0);
        } else {
            #pragma unroll
            for (int mi = 0; mi < 4; ++mi)
                #pragma unroll
                for (int ni = 0; ni < 4; ++ni)
                    acc[mi][ni] = __builtin_amdgcn_mfma_f32_16x16x32_bf16(af[mi], bfv[ni], acc[mi][ni], 0, 0, 0);
        }
    }
    __syncthreads();   // all waves done reading As/Bs before T overwrites

    unsigned short* T = smem;
    int b  = bm >> 12, t0 = bm & 4095;
    int h0 = bn >> 6;
    int slot0 = t0 >> 9;
    int slot1 = 8 + (t0 >> 10);
    int slot2 = 12 + (t0 >> 11);

    if (z < 2) {
        unsigned short* dst = (z == 0) ? Qg : Kg;
        // stage [t][d]: t on l16, d on regs (4 consecutive per quad)
        #pragma unroll
        for (int mi = 0; mi < 4; ++mi) {
            int tl = wm + mi * 16 + l16;
            #pragma unroll
            for (int ni = 0; ni < 4; ++ni) {
                int dl0 = wn + ni * 16 + quad * 4;
                float4 b4 = *reinterpret_cast<const float4*>(&bias[bn + dl0]);
                ushort4 o4;
                o4.x = f2bf(acc[mi][ni][0] + b4.x);
                o4.y = f2bf(acc[mi][ni][1] + b4.y);
                o4.z = f2bf(acc[mi][ni][2] + b4.z);
                o4.w = f2bf(acc[mi][ni][3] + b4.w);
                *reinterpret_cast<ushort4*>(&T[tl * TS + dl0]) = o4;
            }
        }
        __syncthreads();
        // branch 0: per head 128 t x 64 d -> contiguous 16 KB
        #pragma unroll
        for (int rep = 0; rep < 8; ++rep) {
            int c = rep * 256 + tid;
            int h = c >> 10, rr = c & 1023;
            int tl = rr >> 3, dseg = (rr & 7) * 8;
            int bh = b * 16 + h0 + h;
            size_t base = ((size_t)(slot0 * 32 + bh) * 512 + (t0 & 511) + tl) * 64;
            *reinterpret_cast<uint4*>(&dst[base + dseg]) =
                *reinterpret_cast<const uint4*>(&T[tl * TS + h * 64 + dseg]);
        }
        // branch 1: parity-matching t -> contiguous 8 KB per head
        #pragma unroll
        for (int rep = 0; rep < 4; ++rep) {
            int c = rep * 256 + tid;
            int h = c >> 9, rr = c & 511;
            int i = rr >> 3, dseg = (rr & 7) * 8;
            int hh = h0 + h;
            int bh = b * 16 + hh;
            int tl = 2 * i + (hh & 1);
            size_t base = ((size_t)(slot1 * 32 + bh) * 512 + ((t0 & 1023) >> 1) + i) * 64;
            *reinterpret_cast<uint4*>(&dst[base + dseg]) =
                *reinterpret_cast<const uint4*>(&T[tl * TS + h * 64 + dseg]);
        }
        // branch 2: mod-4-matching t -> contiguous 4 KB per head
        #pragma unroll
        for (int rep = 0; rep < 2; ++rep) {
            int c = rep * 256 + tid;
            int h = c >> 8, rr = c & 255;
            int i = rr >> 3, dseg = (rr & 7) * 8;
            int hh = h0 + h;
            int bh = b * 16 + hh;
            int tl = 4 * i + (hh & 3);
            size_t base = ((size_t)(slot2 * 32 + bh) * 512 + ((t0 & 2047) >> 2) + i) * 64;
            *reinterpret_cast<uint4*>(&dst[base + dseg]) =
                *reinterpret_cast<const uint4*>(&T[tl * TS + h * 64 + dseg]);
        }
    } else {
        // stage transposed [d][t]: d on l16, t on regs (4 consecutive per quad)
        #pragma unroll
        for (int ni = 0; ni < 4; ++ni) {
            int dl = wn + ni * 16 + l16;
            float bsv = bias[bn + dl];
            #pragma unroll
            for (int mi = 0; mi < 4; ++mi) {
                int tl0 = wm + mi * 16 + quad * 4;
                ushort4 o4;
                o4.x = f2bf(acc[mi][ni][0] + bsv);
                o4.y = f2bf(acc[mi][ni][1] + bsv);
                o4.z = f2bf(acc[mi][ni][2] + bsv);
                o4.w = f2bf(acc[mi][ni][3] + bsv);
                *reinterpret_cast<ushort4*>(&T[dl * TS + tl0]) = o4;
            }
        }
        __syncthreads();
        // branch 0: per (head,d) 128 t -> 256 B contiguous
        #pragma unroll
        for (int rep = 0; rep < 8; ++rep) {
            int c = rep * 256 + tid;
            int h = c >> 10, rr = c & 1023;
            int d = rr >> 4, seg = (rr & 15) * 8;
            int bh = b * 16 + h0 + h;
            size_t base = ((size_t)(slot0 * 32 + bh) * 64 + d) * 512 + (t0 & 511);
            *reinterpret_cast<uint4*>(&Vtg[base + seg]) =
                *reinterpret_cast<const uint4*>(&T[(h * 64 + d) * TS + seg]);
        }
        // branch 1: stride-2 LDS gather, contiguous 128 B per (head,d)
        #pragma unroll
        for (int rep = 0; rep < 4; ++rep) {
            int c = rep * 256 + tid;
            int h = c >> 9, rr = c & 511;
            int d = rr >> 3, seg = rr & 7;
            int hh = h0 + h;
            int bh = b * 16 + hh;
            int p = hh & 1;
            const unsigned short* srw = &T[(h * 64 + d) * TS];
            unsigned short buf[8];
            #pragma unroll
            for (int j = 0; j < 8; ++j) buf[j] = srw[p + 2 * (seg * 8 + j)];
            size_t base = ((size_t)(slot1 * 32 + bh) * 64 + d) * 512 + ((t0 & 1023) >> 1);
            *reinterpret_cast<uint4*>(&Vtg[base + seg * 8]) = *reinterpret_cast<const uint4*>(buf);
        }
        // branch 2: stride-4 LDS gather, contiguous 64 B per (head,d)
        #pragma unroll
        for (int rep = 0; rep < 2; ++rep) {
            int c = rep * 256 + tid;
            int h = c >> 8, rr = c & 255;
            int d = rr >> 2, seg = rr & 3;
            int hh = h0 + h;
            int bh = b * 16 + hh;
            int p = hh & 3;
            const unsigned short* srw = &T[(h * 64 + d) * TS];
            unsigned short buf[8];
            #pragma unroll
            for (int j = 0; j < 8; ++j) buf[j] = srw[p + 4 * (seg * 8 + j)];
            size_t base = ((size_t)(slot2 * 32 + bh) * 64 + d) * 512 + ((t0 & 2047) >> 2);
            *reinterpret_cast<uint4*>(&Vtg[base + seg * 8]) = *reinterpret_cast<const uint4*>(buf);
        }
    }
}

// ---------------- dilated attention: swapped QK^T (S^T) + permuted-K staging => P stays in-register ----------------
__global__ __launch_bounds__(256, 3) void k_attn(
    const unsigned short* __restrict__ Qg,
    const unsigned short* __restrict__ Kg,
    const unsigned short* __restrict__ Vtg,
    unsigned short* __restrict__ Og,
    float* __restrict__ Lg)
{
    __shared__ unsigned short Ks[2][64 * 72];
    __shared__ unsigned short Vs[2][64 * 72];      // [d][kcol] (pre-transposed in global)

    int tid  = threadIdx.x;
    int lane = tid & 63, wv = tid >> 6;
    int quad = lane >> 4, l16 = lane & 15;
    int q8   = quad << 3;
    int pq = blockIdx.x, ys = blockIdx.y, bh = blockIdx.z;
    int jt_end = 2 * (3 - pq) + 1;    // 7 (pair 0,3) or 5 (pair 1,2)
    size_t sb = (size_t)(ys * 32 + bh) * (512 * 64);
    const unsigned short* qp = Qg + sb;
    const unsigned short* kp = Kg + sb;
    const unsigned short* vp = Vtg + sb;
    unsigned short* op = Og + sb;
    float* lp = Lg + (size_t)(ys * 32 + bh) * 512;

    int rw[2] = { pq * 128 + wv * 32, (3 - pq) * 128 + wv * 32 };

    // staging geometry: thread covers rows {srow, srow+32} cols sc8..sc8+7
    int srow = tid >> 3, sc8 = (tid & 7) * 8;
    // K-row permutation (bijective on 0..31): makes S^T output k-slots land in natural PV order.
    int prow = ((srow >> 2) & 1) * 16 + ((srow >> 3) & 3) * 4 + (srow & 3);
    uint4 kr[2], vr[2];
    {   // preload jt = 0
        #pragma unroll
        for (int s = 0; s < 2; ++s) {
            int row = s * 32 + srow;
            kr[s] = *reinterpret_cast<const uint4*>(&kp[(size_t)row * 64 + sc8]);
            vr[s] = *reinterpret_cast<const uint4*>(&vp[(size_t)row * 512 + sc8]);
        }
    }

    bf16x8 qf[2][2][2];
    #pragma unroll
    for (int qi = 0; qi < 2; ++qi)
        #pragma unroll
        for (int m16 = 0; m16 < 2; ++m16)
            #pragma unroll
            for (int kk = 0; kk < 2; ++kk)
                qf[qi][m16][kk] = *reinterpret_cast<const bf16x8*>(
                    &qp[(size_t)(rw[qi] + m16 * 16 + l16) * 64 + kk * 32 + quad * 8]);

    f32x4 acc[2][2][4] = {};
    float l4[2][2] = {};

    for (int jt = 0; jt <= jt_end; ++jt) {
        unsigned short* Kb = &Ks[jt & 1][0];
        unsigned short* Vb = &Vs[jt & 1][0];
        #pragma unroll
        for (int s = 0; s < 2; ++s) {
            *reinterpret_cast<uint4*>(&Kb[(s * 32 + prow) * 72 + sc8]) = kr[s];
            *reinterpret_cast<uint4*>(&Vb[(s * 32 + srow) * 72 + sc8]) = vr[s];
        }
        if (jt < jt_end) {   // prefetch next tile into regs; loads fly during compute below
            #pragma unroll
            for (int s = 0; s < 2; ++s) {
                int row = s * 32 + srow;
                kr[s] = *reinterpret_cast<const uint4*>(&kp[(size_t)((jt + 1) * 64 + row) * 64 + sc8]);
                vr[s] = *reinterpret_cast<const uint4*>(&vp[(size_t)row * 512 + (jt + 1) * 64 + sc8]);
            }
        }
        __syncthreads();     // dbuf: single barrier per jt

        #pragma unroll
        for (int qi = 0; qi < 2; ++qi) {
            #pragma unroll
            for (int m16 = 0; m16 < 2; ++m16) {
                int rowbase = rw[qi] + m16 * 16;
                if (jt * 64 > rowbase + 15) continue;

                // S^T = mfma(K, Q): lane holds S[q=l16][k = jt*64 + (nt>>1)*32 + quad*8 + (nt&1)*4 + ri]
                f32x4 sacc[4];
                __builtin_amdgcn_s_setprio(1);
                #pragma unroll
                for (int nt = 0; nt < 4; ++nt) {
                    bf16x8 b0 = *reinterpret_cast<const bf16x8*>(&Kb[(nt * 16 + l16) * 72 + quad * 8]);
                    bf16x8 b1 = *reinterpret_cast<const bf16x8*>(&Kb[(nt * 16 + l16) * 72 + 32 + quad * 8]);
                    f32x4 s4 = {};
                    s4 = __builtin_amdgcn_mfma_f32_16x16x32_bf16(b0, qf[qi][m16][0], s4, 0, 0, 0);
                    s4 = __builtin_amdgcn_mfma_f32_16x16x32_bf16(b1, qf[qi][m16][1], s4, 0, 0, 0);
                    sacc[nt] = s4;
                }
                __builtin_amdgcn_s_setprio(0);

                if (jt * 64 + 63 > rowbase) {
                    int qrow = rowbase + l16;
                    #pragma unroll
                    for (int nt = 0; nt < 4; ++nt)
                        #pragma unroll
                        for (int ri = 0; ri < 4; ++ri) {
                            int kj = jt * 64 + (nt >> 1) * 32 + (nt & 1) * 4 + q8 + ri;
                            if (kj > qrow) sacc[nt][ri] = -1e30f;
                        }
                }
                float ls = 0.f;
                #pragma unroll
                for (int nt = 0; nt < 4; ++nt)
                    #pragma unroll
                    for (int ri = 0; ri < 4; ++ri) {
                        float p = __builtin_amdgcn_exp2f(sacc[nt][ri]);
                        sacc[nt][ri] = p;
                        ls += p;
                    }
                l4[qi][m16] += ls;

                // P -> bf16 A-fragments: fully lane-local, naturally ordered (thanks to K permute)
                union { unsigned int u[4]; bf16x8 v; } p0u, p1u;
                asm("v_cvt_pk_bf16_f32 %0, %1, %2" : "=v"(p0u.u[0]) : "v"(sacc[0][0]), "v"(sacc[0][1]));
                asm("v_cvt_pk_bf16_f32 %0, %1, %2" : "=v"(p0u.u[1]) : "v"(sacc[0][2]), "v"(sacc[0][3]));
                asm("v_cvt_pk_bf16_f32 %0, %1, %2" : "=v"(p0u.u[2]) : "v"(sacc[1][0]), "v"(sacc[1][1]));
                asm("v_cvt_pk_bf16_f32 %0, %1, %2" : "=v"(p0u.u[3]) : "v"(sacc[1][2]), "v"(sacc[1][3]));
                asm("v_cvt_pk_bf16_f32 %0, %1, %2" : "=v"(p1u.u[0]) : "v"(sacc[2][0]), "v"(sacc[2][1]));
                asm("v_cvt_pk_bf16_f32 %0, %1, %2" : "=v"(p1u.u[1]) : "v"(sacc[2][2]), "v"(sacc[2][3]));
                asm("v_cvt_pk_bf16_f32 %0, %1, %2" : "=v"(p1u.u[2]) : "v"(sacc[3][0]), "v"(sacc[3][1]));
                asm("v_cvt_pk_bf16_f32 %0, %1, %2" : "=v"(p1u.u[3]) : "v"(sacc[3][2]), "v"(sacc[3][3]));

                __builtin_amdgcn_s_setprio(1);
                #pragma unroll
                for (int dt = 0; dt < 4; ++dt) {
                    bf16x8 v0 = *reinterpret_cast<const bf16x8*>(&Vb[(dt * 16 + l16) * 72 + quad * 8]);
                    bf16x8 v1 = *reinterpret_cast<const bf16x8*>(&Vb[(dt * 16 + l16) * 72 + 32 + quad * 8]);
                    f32x4 a4 = acc[qi][m16][dt];
                    a4 = __builtin_amdgcn_mfma_f32_16x16x32_bf16(p0u.v, v0, a4, 0, 0, 0);
                    a4 = __builtin_amdgcn_mfma_f32_16x16x32_bf16(p1u.v, v1, a4, 0, 0, 0);
                    acc[qi][m16][dt] = a4;
                }
                __builtin_amdgcn_s_setprio(0);
            }
        }
    }

    #pragma unroll
    for (int qi = 0; qi < 2; ++qi)
        #pragma unroll
        for (int m16 = 0; m16 < 2; ++m16) {
            int rowb = rw[qi] + m16 * 16;
            float L = l4[qi][m16];
            L += __shfl_xor(L, 16);
            L += __shfl_xor(L, 32);       // full row sum for q-row rowb + l16 (dup across quads)
            float inv[4];
            #pragma unroll
            for (int ri = 0; ri < 4; ++ri)
                inv[ri] = 1.f / __shfl(L, quad * 4 + ri);
            #pragma unroll
            for (int dt = 0; dt < 4; ++dt)
                #pragma unroll
                for (int ri = 0; ri < 4; ++ri) {
                    int row = rowb + quad * 4 + ri;
                    op[(size_t)row * 64 + dt * 16 + l16] = f2bf(acc[qi][m16][dt][ri] * inv[ri]);
                }
            if (lane < 16)
                lp[rowb + l16] = __logf(L);
        }
}

// ---------------- combine branches via LSE weights ----------------
__global__ void k_combine(const unsigned short* __restrict__ Og,
                          const float* __restrict__ Lg,
                          unsigned short* __restrict__ yb)
{
    int g   = blockIdx.x * blockDim.x + threadIdx.x;
    int row = g >> 3;
    int d0  = (g & 7) * 8;
    int bh = row >> 12, t = row & 4095;
    int b = bh >> 4, h = bh & 15;

    int slot0 = t >> 9,         idx0 = t & 511;
    int slot1 = 8 + (t >> 10),  idx1 = (t & 1023) >> 1;
    int slot2 = 12 + (t >> 11), idx2 = (t & 2047) >> 2;
    size_t r0 = (size_t)(slot0 * 32 + bh) * 512 + idx0;
    size_t r1 = (size_t)(slot1 * 32 + bh) * 512 + idx1;
    size_t r2 = (size_t)(slot2 * 32 + bh) * 512 + idx2;
    bool c1 = ((t ^ h) & 1) == 0;
    bool c2 = ((t ^ h) & 3) == 0;

    float L0 = Lg[r0];
    float L1 = c1 ? Lg[r1] : -1e30f;
    float L2 = c2 ? Lg[r2] : -1e30f;
    float m  = fmaxf(L0, fmaxf(L1, L2));
    float w0 = __expf(L0 - m), w1 = __expf(L1 - m), w2 = __expf(L2 - m);
    float inv = 1.f / (w0 + w1 + w2);

    uint4 v0 = *reinterpret_cast<const uint4*>(&Og[r0 * 64 + d0]);
    uint4 v1 = *reinterpret_cast<const uint4*>(&Og[r1 * 64 + d0]);
    uint4 v2 = *reinterpret_cast<const uint4*>(&Og[r2 * 64 + d0]);
    const unsigned short* p0 = reinterpret_cast<const unsigned short*>(&v0);
    const unsigned short* p1 = reinterpret_cast<const unsigned short*>(&v1);
    const unsigned short* p2 = reinterpret_cast<const unsigned short*>(&v2);
    unsigned short o[8];
    #pragma unroll
    for (int u = 0; u < 8; ++u)
        o[u] = f2bf((w0 * bf2f(p0[u]) + w1 * bf2f(p1[u]) + w2 * bf2f(p2[u])) * inv);
    size_t yidx = (((size_t)b * 4096 + t) * 1024) + (size_t)h * 64 + d0;
    *reinterpret_cast<uint4*>(&yb[yidx]) = *reinterpret_cast<const uint4*>(o);
}

extern "C" void kernel_launch(void* const* d_in, const int* in_sizes, int n_in,
                              void* d_out, int out_size, void* d_ws, size_t ws_size,
                              hipStream_t stream)
{
    const float* x        = (const float*)d_in[0];
    const float* c_attn_w = (const float*)d_in[1];
    const float* c_attn_b = (const float*)d_in[2];
    const float* q_w      = (const float*)d_in[3];
    const float* q_b      = (const float*)d_in[4];
    const float* k_w      = (const float*)d_in[5];
    const float* k_b      = (const float*)d_in[6];
    const float* v_w      = (const float*)d_in[7];
    const float* v_b      = (const float*)d_in[8];
    const float* o_w      = (const float*)d_in[9];
    const float* o_b      = (const float*)d_in[10];

    char* ws = (char*)d_ws;
    size_t off = 0;
    auto alloc = [&](size_t bytes) -> char* {
        char* p = ws + off; off += (bytes + 255) & ~(size_t)255; return p;
    };
    const size_t GSZ = 14ull * 32 * 512 * 64;
    unsigned short* xb    = (unsigned short*)alloc(8192ull * 1024 * 2);
    unsigned short* WcB   = (unsigned short*)alloc(1024ull * 3072 * 2);   // c_attn_w bf16, untransposed
    unsigned short* wqT   = (unsigned short*)alloc(1024ull * 1024 * 2);   // q/k/v contiguous
    unsigned short* wkT   = (unsigned short*)alloc(1024ull * 1024 * 2);
    unsigned short* wvT   = (unsigned short*)alloc(1024ull * 1024 * 2);
    unsigned short* woT   = (unsigned short*)alloc(1024ull * 1024 * 2);
    unsigned short* Weff  = (unsigned short*)alloc(3ull * 1024 * 1024 * 2);
    float*          beff  = (float*)alloc(3ull * 1024 * 4);
    unsigned short* Qg    = (unsigned short*)alloc(GSZ * 2);
    unsigned short* Kg    = (unsigned short*)alloc(GSZ * 2);
    unsigned short* Vtg   = (unsigned short*)alloc(GSZ * 2);
    unsigned short* Og    = (unsigned short*)alloc(GSZ * 2);
    float*          Lg    = (float*)alloc(14ull * 32 * 512 * 4);
    unsigned short* yb    = xb;   // alias: xb dead after k_gemm3
    (void)wkT; (void)wvT;

    // 1. fused casts (x -> xb, c_attn_w -> WcB) in one dispatch
    k_cast2<<<8192 + 3072, 256, 0, stream>>>(x, xb, c_attn_w, WcB);
    // 2. transpose-cast q/k/v/o weights (one dispatch)
    k_transpose4<<<dim3(32, 32, 4), dim3(32, 8), 0, stream>>>(q_w, k_w, v_w, o_w, wqT, wkT, wvT, woT);
    // 3. weight/bias folding
    k_foldw<<<dim3(8, 8, 3), 256, 0, stream>>>(wqT, WcB, Weff);
    k_foldb<<<768, 256, 0, stream>>>(wqT, c_attn_b, q_b, k_b, v_b, beff);
    // 4. fused projections: x -> gathered Q/K/V^T (LDS dbuf prefetch-after-barrier, XCD swizzle)
    k_gemm3<<<dim3(8, 64, 3), 256, 0, stream>>>(xb, Weff, beff, Qg, Kg, Vtg);
    // 5. attention (swapped-QK in-register P, dbuf K/V, single barrier per tile)
    k_attn<<<dim3(2, 14, 32), 256, 0, stream>>>(Qg, Kg, Vtg, Og, Lg);
    // 6. combine -> y
    k_combine<<<4096, 256, 0, stream>>>(Og, Lg, yb);
    // 7. out = y @ o_w + o_b (fp32, LDS dbuf prefetch-after-barrier)
    k_gemm<<<dim3(8, 64), 256, 0, stream>>>(yb, 1024, woT, 1024, o_b, d_out, 8192, 1024, 1024, 2, 1.f);
}

// Round 7
// 308.182 us; speedup vs baseline: 1.2135x; 1.0757x over previous
//
#include <hip/hip_runtime.h>
#include <hip/hip_bf16.h>

typedef __bf16 bf16x8 __attribute__((ext_vector_type(8)));
typedef float  f32x4  __attribute__((ext_vector_type(4)));

__device__ __forceinline__ unsigned short f2bf(float f) {
    union { float f; unsigned int u; } v; v.f = f;
    return (unsigned short)((v.u + 0x8000u) >> 16);   // round-half-up: 2 VALU
}
__device__ __forceinline__ float bf2f(unsigned short h) {
    union { unsigned int u; float f; } v; v.u = ((unsigned int)h) << 16;
    return v.f;
}

typedef __attribute__((address_space(3))) unsigned int lds_u32_t;
typedef const __attribute__((address_space(1))) unsigned int glb_u32_t;
__device__ __forceinline__ void gl_lds16(const void* g, void* l) {
    __builtin_amdgcn_global_load_lds((glb_u32_t*)g, (lds_u32_t*)l, 16, 0, 0);
}

// ---------------- prep: fused casts (x, c_attn_w) + 4x transpose-cast of q/k/v/o weights ----------------
// blocks [0, 11264): flat fp32->bf16 casts; blocks [11264, 15360): 32x32 transpose tiles.
__global__ __launch_bounds__(256) void k_prep(
    const float* __restrict__ x,  unsigned short* __restrict__ xb,
    const float* __restrict__ cw, unsigned short* __restrict__ wcb,
    const float* __restrict__ s0, const float* __restrict__ s1,
    const float* __restrict__ s2, const float* __restrict__ s3,
    unsigned short* __restrict__ d0, unsigned short* __restrict__ d1,
    unsigned short* __restrict__ d2, unsigned short* __restrict__ d3)
{
    __shared__ float tile[32][33];
    int blk = blockIdx.x;
    if (blk < 11264) {
        const float* in;
        unsigned short* out;
        int base;
        if (blk < 8192) { in = x;  out = xb;  base = blk * 1024; }
        else            { in = cw; out = wcb; base = (blk - 8192) * 1024; }
        int i = base + threadIdx.x * 4;
        float4 v = *reinterpret_cast<const float4*>(in + i);
        ushort4 o;
        o.x = f2bf(v.x); o.y = f2bf(v.y); o.z = f2bf(v.z); o.w = f2bf(v.w);
        *reinterpret_cast<ushort4*>(out + i) = o;
    } else {
        int t = blk - 11264;
        int z = t >> 10, rem = t & 1023;
        int bx = rem & 31, by = rem >> 5;
        const float* in = (z == 0) ? s0 : (z == 1) ? s1 : (z == 2) ? s2 : s3;
        unsigned short* out = (z == 0) ? d0 : (z == 1) ? d1 : (z == 2) ? d2 : d3;
        int n0 = bx * 32, k0 = by * 32;
        int tx = threadIdx.x & 31, ty = threadIdx.x >> 5;   // (32,8)
        #pragma unroll
        for (int i = 0; i < 4; ++i)
            tile[ty + i * 8][tx] = in[(size_t)(k0 + ty + i * 8) * 1024 + n0 + tx];
        __syncthreads();
        #pragma unroll
        for (int i = 0; i < 4; ++i)
            out[(size_t)(n0 + ty + i * 8) * 1024 + k0 + tx] = f2bf(tile[tx][ty + i * 8]);
    }
}

// ---------------- bf16 MFMA GEMM (BK=64, swapped operands): out = A[M,K] * Bt[N,K]^T + bias ----------------
// Round-4 config (best measured): two kk-subtiles of the 64B-row layout, 2 barriers per 64-K.
// mode 0: out bf16 row-major [M,N];  mode 2: out fp32 row-major [M,N]
__global__ __launch_bounds__(256) void k_gemm(
    const unsigned short* __restrict__ A, int lda,
    const unsigned short* __restrict__ Bt, int ldb,
    const float* __restrict__ bias,
    void* __restrict__ out,
    int M, int N, int K, int mode, float scale)
{
    __shared__ unsigned short As[8192];   // [2 kk][128][32]
    __shared__ unsigned short Bs[8192];
    int tid  = threadIdx.x;
    int lane = tid & 63, wv = tid >> 6;
    int quad = lane >> 4, l16 = lane & 15;

    // XCD-aware chunked swizzle (bijective when nwg % 8 == 0)
    int nwg = gridDim.x * gridDim.y;
    int lin = blockIdx.y * gridDim.x + blockIdx.x;
    int bx = blockIdx.x, by = blockIdx.y;
    if ((nwg & 7) == 0) {
        int swz = (lin & 7) * (nwg >> 3) + (lin >> 3);
        bx = swz % gridDim.x;
        by = swz / gridDim.x;
    }
    int bm = by * 128, bn = bx * 128;
    int wm = (wv >> 1) * 64,  wn = (wv & 1) * 64;

    f32x4 acc[4][4] = {};
    int srow = tid >> 2, scol = (tid & 3) * 8;

    for (int k0 = 0; k0 < K; k0 += 64) {
        #pragma unroll
        for (int kk = 0; kk < 2; ++kk)
            #pragma unroll
            for (int s = 0; s < 2; ++s) {
                int row = s * 64 + srow;
                gl_lds16(&A[(size_t)(bm + row) * lda + k0 + kk * 32 + scol], &As[kk * 4096 + (s * 256 + wv * 64) * 8]);
                gl_lds16(&Bt[(size_t)(bn + row) * ldb + k0 + kk * 32 + scol], &Bs[kk * 4096 + (s * 256 + wv * 64) * 8]);
            }
        __syncthreads();
        #pragma unroll
        for (int kk = 0; kk < 2; ++kk) {
            bf16x8 af[4], bfv[4];
            #pragma unroll
            for (int mi = 0; mi < 4; ++mi)
                af[mi] = *reinterpret_cast<const bf16x8*>(&As[kk * 4096 + (wm + mi * 16 + l16) * 32 + quad * 8]);
            #pragma unroll
            for (int ni = 0; ni < 4; ++ni)
                bfv[ni] = *reinterpret_cast<const bf16x8*>(&Bs[kk * 4096 + (wn + ni * 16 + l16) * 32 + quad * 8]);
            #pragma unroll
            for (int mi = 0; mi < 4; ++mi)
                #pragma unroll
                for (int ni = 0; ni < 4; ++ni)
                    acc[mi][ni] = __builtin_amdgcn_mfma_f32_16x16x32_bf16(bfv[ni], af[mi], acc[mi][ni], 0, 0, 0);
        }
        __syncthreads();
    }

    #pragma unroll
    for (int mi = 0; mi < 4; ++mi) {
        int row = bm + wm + mi * 16 + l16;
        #pragma unroll
        for (int ni = 0; ni < 4; ++ni) {
            int col0 = bn + wn + ni * 16 + quad * 4;
            float4 b4 = *reinterpret_cast<const float4*>(&bias[col0]);
            float v0 = (acc[mi][ni][0] + b4.x) * scale;
            float v1 = (acc[mi][ni][1] + b4.y) * scale;
            float v2 = (acc[mi][ni][2] + b4.z) * scale;
            float v3 = (acc[mi][ni][3] + b4.w) * scale;
            if (mode == 0) {
                ushort4 o4; o4.x = f2bf(v0); o4.y = f2bf(v1); o4.z = f2bf(v2); o4.w = f2bf(v3);
                *reinterpret_cast<ushort4*>(&reinterpret_cast<unsigned short*>(out)[(size_t)row * N + col0]) = o4;
            } else {
                float4 o4; o4.x = v0; o4.y = v1; o4.z = v2; o4.w = v3;
                *reinterpret_cast<float4*>(&reinterpret_cast<float*>(out)[(size_t)row * N + col0]) = o4;
            }
        }
    }
}

// ---------------- fused weight+bias fold in ONE dispatch ----------------
// blocks [0,192): W_eff^T[z] = wT[z] @ WcB[:, z*1024 +: 1024]  (BK=64, round-4 config)
// blocks [192,960): bias fold, one wave per output (vectorized + shuffle reduce)
__global__ __launch_bounds__(256) void k_foldwb(
    const unsigned short* __restrict__ wT3,
    const unsigned short* __restrict__ WcB,
    unsigned short* __restrict__ Weff,
    const float* __restrict__ bc,
    const float* __restrict__ qb, const float* __restrict__ kb,
    const float* __restrict__ vb, float* __restrict__ beff)
{
    __shared__ unsigned short As[8192];
    __shared__ unsigned short Bs[8192];
    int blk = blockIdx.x;
    int tid  = threadIdx.x;
    int lane = tid & 63, wv = tid >> 6;

    if (blk < 192) {
        int z = blk / 64, r = blk % 64;
        int by = r >> 3, bx = r & 7;
        const unsigned short* A  = wT3 + (size_t)z * 1024 * 1024;
        const unsigned short* Bt = WcB + z * 1024;
        unsigned short* out = Weff + (size_t)z * 1024 * 1024;
        float scale = (z == 0) ? 0.1803368801f : 1.f;

        int quad = lane >> 4, l16 = lane & 15;
        int bm = by * 128, bn = bx * 128;
        int wm = (wv >> 1) * 64,  wn = (wv & 1) * 64;

        f32x4 acc[4][4] = {};
        int srow = tid >> 2, scol = (tid & 3) * 8;

        for (int k0 = 0; k0 < 1024; k0 += 64) {
            #pragma unroll
            for (int kk = 0; kk < 2; ++kk)
                #pragma unroll
                for (int s = 0; s < 2; ++s) {
                    int row = s * 64 + srow;
                    gl_lds16(&A[(size_t)(bm + row) * 1024 + k0 + kk * 32 + scol], &As[kk * 4096 + (s * 256 + wv * 64) * 8]);
                    gl_lds16(&Bt[(size_t)(bn + row) * 3072 + k0 + kk * 32 + scol], &Bs[kk * 4096 + (s * 256 + wv * 64) * 8]);
                }
            __syncthreads();
            #pragma unroll
            for (int kk = 0; kk < 2; ++kk) {
                bf16x8 af[4], bfv[4];
                #pragma unroll
                for (int mi = 0; mi < 4; ++mi)
                    af[mi] = *reinterpret_cast<const bf16x8*>(&As[kk * 4096 + (wm + mi * 16 + l16) * 32 + quad * 8]);
                #pragma unroll
                for (int ni = 0; ni < 4; ++ni)
                    bfv[ni] = *reinterpret_cast<const bf16x8*>(&Bs[kk * 4096 + (wn + ni * 16 + l16) * 32 + quad * 8]);
                #pragma unroll
                for (int mi = 0; mi < 4; ++mi)
                    #pragma unroll
                    for (int ni = 0; ni < 4; ++ni)
                        acc[mi][ni] = __builtin_amdgcn_mfma_f32_16x16x32_bf16(bfv[ni], af[mi], acc[mi][ni], 0, 0, 0);
            }
            __syncthreads();
        }

        int quad4 = quad * 4;
        #pragma unroll
        for (int mi = 0; mi < 4; ++mi) {
            int row = bm + wm + mi * 16 + l16;
            #pragma unroll
            for (int ni = 0; ni < 4; ++ni) {
                int col0 = bn + wn + ni * 16 + quad4;
                ushort4 o4;
                o4.x = f2bf(acc[mi][ni][0] * scale);
                o4.y = f2bf(acc[mi][ni][1] * scale);
                o4.z = f2bf(acc[mi][ni][2] * scale);
                o4.w = f2bf(acc[mi][ni][3] * scale);
                *reinterpret_cast<ushort4*>(&out[(size_t)row * 1024 + col0]) = o4;
            }
        }
    } else {
        int id = (blk - 192) * 4 + wv;   // 0..3071
        int z = id >> 10, n = id & 1023;
        const unsigned short* row = wT3 + (size_t)z * 1024 * 1024 + (size_t)n * 1024;
        const float* bcz = bc + z * 1024;
        float s = 0.f;
        #pragma unroll
        for (int it = 0; it < 2; ++it) {
            int c0 = it * 512 + lane * 8;
            uint4 v = *reinterpret_cast<const uint4*>(&row[c0]);
            const unsigned short* pv = reinterpret_cast<const unsigned short*>(&v);
            float4 f0 = *reinterpret_cast<const float4*>(&bcz[c0]);
            float4 f1 = *reinterpret_cast<const float4*>(&bcz[c0 + 4]);
            s += f0.x * bf2f(pv[0]) + f0.y * bf2f(pv[1]) + f0.z * bf2f(pv[2]) + f0.w * bf2f(pv[3]);
            s += f1.x * bf2f(pv[4]) + f1.y * bf2f(pv[5]) + f1.z * bf2f(pv[6]) + f1.w * bf2f(pv[7]);
        }
        s += __shfl_xor(s, 1); s += __shfl_xor(s, 2); s += __shfl_xor(s, 4);
        s += __shfl_xor(s, 8); s += __shfl_xor(s, 16); s += __shfl_xor(s, 32);
        if (lane == 0) {
            const float* b2 = (z == 0) ? qb : (z == 1) ? kb : vb;
            float r = s + b2[n];
            if (z == 0) r *= 0.1803368801f;
            beff[id] = r;
        }
    }
}

// ---------------- fused projections: x @ W_eff[z] + b_eff[z] -> gathered layouts ----------------
// K-loop (BK=64, round-4 config): z<2 swapped mfma(B,A) [t on lanes, d on regs]; z==2 normal.
// Epilogue: stage full 128x128 tile in LDS (As/Bs dead), then branch regions copied out as
// fully-contiguous bulk writes (consecutive t -> consecutive idx => 16/8/4 KB contiguous per head).
__global__ __launch_bounds__(256) void k_gemm3(
    const unsigned short* __restrict__ A,      // xb [8192][1024]
    const unsigned short* __restrict__ Weff,   // [3][1024][1024]
    const float* __restrict__ beff,            // [3][1024]
    unsigned short* __restrict__ Qg, unsigned short* __restrict__ Kg,
    unsigned short* __restrict__ Vtg)
{
    __shared__ unsigned short smem[16896];     // As(8192)+Bs(8192) in loop; T[128][132] in epilogue
    unsigned short* As = smem;
    unsigned short* Bs = smem + 8192;
    const int TS = 132;

    int tid  = threadIdx.x;
    int lane = tid & 63, wv = tid >> 6;
    int quad = lane >> 4, l16 = lane & 15;

    // XCD-aware chunked swizzle (nwg = 1536, % 8 == 0 -> bijective); grid dims known: (8,64,3)
    int nwg = gridDim.x * gridDim.y * gridDim.z;
    int lin = (blockIdx.z * gridDim.y + blockIdx.y) * gridDim.x + blockIdx.x;
    int swz = (lin & 7) * (nwg >> 3) + (lin >> 3);
    int bx  = swz & 7;
    int tmp = swz >> 3;
    int by  = tmp & 63;
    int z   = tmp >> 6;

    const unsigned short* Bt = Weff + (size_t)z * 1024 * 1024;
    const float* bias = beff + z * 1024;

    int bm = by * 128, bn = bx * 128;
    int wm = (wv >> 1) * 64,  wn = (wv & 1) * 64;

    f32x4 acc[4][4] = {};
    int srow = tid >> 2, scol = (tid & 3) * 8;

    for (int k0 = 0; k0 < 1024; k0 += 64) {
        #pragma unroll
        for (int kk = 0; kk < 2; ++kk)
            #pragma unroll
            for (int s = 0; s < 2; ++s) {
                int row = s * 64 + srow;
                gl_lds16(&A[(size_t)(bm + row) * 1024 + k0 + kk * 32 + scol], &As[kk * 4096 + (s * 256 + wv * 64) * 8]);
                gl_lds16(&Bt[(size_t)(bn + row) * 1024 + k0 + kk * 32 + scol], &Bs[kk * 4096 + (s * 256 + wv * 64) * 8]);
            }
        __syncthreads();
        #pragma unroll
        for (int kk = 0; kk < 2; ++kk) {
            bf16x8 af[4], bfv[4];
            #pragma unroll
            for (int mi = 0; mi < 4; ++mi)
                af[mi] = *reinterpret_cast<const bf16x8*>(&As[kk * 4096 + (wm + mi * 16 + l16) * 32 + quad * 8]);
            #pragma unroll
            for (int ni = 0; ni < 4; ++ni)
                bfv[ni] = *reinterpret_cast<const bf16x8*>(&Bs[kk * 4096 + (wn + ni * 16 + l16) * 32 + quad * 8]);
            if (z < 2) {
                #pragma unroll
                for (int mi = 0; mi < 4; ++mi)
                    #pragma unroll
                    for (int ni = 0; ni < 4; ++ni)
                        acc[mi][ni] = __builtin_amdgcn_mfma_f32_16x16x32_bf16(bfv[ni], af[mi], acc[mi][ni], 0, 0, 0);
            } else {
                #pragma unroll
                for (int mi = 0; mi < 4; ++mi)
                    #pragma unroll
                    for (int ni = 0; ni < 4; ++ni)
                        acc[mi][ni] = __builtin_amdgcn_mfma_f32_16x16x32_bf16(af[mi], bfv[ni], acc[mi][ni], 0, 0, 0);
            }
        }
        __syncthreads();
    }

    unsigned short* T = smem;
    int b  = bm >> 12, t0 = bm & 4095;
    int h0 = bn >> 6;
    int slot0 = t0 >> 9;
    int slot1 = 8 + (t0 >> 10);
    int slot2 = 12 + (t0 >> 11);

    if (z < 2) {
        unsigned short* dst = (z == 0) ? Qg : Kg;
        // stage [t][d]: t on l16, d on regs (4 consecutive per quad)
        #pragma unroll
        for (int mi = 0; mi < 4; ++mi) {
            int tl = wm + mi * 16 + l16;
            #pragma unroll
            for (int ni = 0; ni < 4; ++ni) {
                int dl0 = wn + ni * 16 + quad * 4;
                float4 b4 = *reinterpret_cast<const float4*>(&bias[bn + dl0]);
                ushort4 o4;
                o4.x = f2bf(acc[mi][ni][0] + b4.x);
                o4.y = f2bf(acc[mi][ni][1] + b4.y);
                o4.z = f2bf(acc[mi][ni][2] + b4.z);
                o4.w = f2bf(acc[mi][ni][3] + b4.w);
                *reinterpret_cast<ushort4*>(&T[tl * TS + dl0]) = o4;
            }
        }
        __syncthreads();
        // branch 0: per head 128 t x 64 d -> contiguous 16 KB
        #pragma unroll
        for (int rep = 0; rep < 8; ++rep) {
            int c = rep * 256 + tid;
            int h = c >> 10, rr = c & 1023;
            int tl = rr >> 3, dseg = (rr & 7) * 8;
            int bh = b * 16 + h0 + h;
            size_t base = ((size_t)(slot0 * 32 + bh) * 512 + (t0 & 511) + tl) * 64;
            *reinterpret_cast<uint4*>(&dst[base + dseg]) =
                *reinterpret_cast<const uint4*>(&T[tl * TS + h * 64 + dseg]);
        }
        // branch 1: parity-matching t -> contiguous 8 KB per head
        #pragma unroll
        for (int rep = 0; rep < 4; ++rep) {
            int c = rep * 256 + tid;
            int h = c >> 9, rr = c & 511;
            int i = rr >> 3, dseg = (rr & 7) * 8;
            int hh = h0 + h;
            int bh = b * 16 + hh;
            int tl = 2 * i + (hh & 1);
            size_t base = ((size_t)(slot1 * 32 + bh) * 512 + ((t0 & 1023) >> 1) + i) * 64;
            *reinterpret_cast<uint4*>(&dst[base + dseg]) =
                *reinterpret_cast<const uint4*>(&T[tl * TS + h * 64 + dseg]);
        }
        // branch 2: mod-4-matching t -> contiguous 4 KB per head
        #pragma unroll
        for (int rep = 0; rep < 2; ++rep) {
            int c = rep * 256 + tid;
            int h = c >> 8, rr = c & 255;
            int i = rr >> 3, dseg = (rr & 7) * 8;
            int hh = h0 + h;
            int bh = b * 16 + hh;
            int tl = 4 * i + (hh & 3);
            size_t base = ((size_t)(slot2 * 32 + bh) * 512 + ((t0 & 2047) >> 2) + i) * 64;
            *reinterpret_cast<uint4*>(&dst[base + dseg]) =
                *reinterpret_cast<const uint4*>(&T[tl * TS + h * 64 + dseg]);
        }
    } else {
        // stage transposed [d][t]: d on l16, t on regs (4 consecutive per quad)
        #pragma unroll
        for (int ni = 0; ni < 4; ++ni) {
            int dl = wn + ni * 16 + l16;
            float bsv = bias[bn + dl];
            #pragma unroll
            for (int mi = 0; mi < 4; ++mi) {
                int tl0 = wm + mi * 16 + quad * 4;
                ushort4 o4;
                o4.x = f2bf(acc[mi][ni][0] + bsv);
                o4.y = f2bf(acc[mi][ni][1] + bsv);
                o4.z = f2bf(acc[mi][ni][2] + bsv);
                o4.w = f2bf(acc[mi][ni][3] + bsv);
                *reinterpret_cast<ushort4*>(&T[dl * TS + tl0]) = o4;
            }
        }
        __syncthreads();
        // branch 0: per (head,d) 128 t -> 256 B contiguous
        #pragma unroll
        for (int rep = 0; rep < 8; ++rep) {
            int c = rep * 256 + tid;
            int h = c >> 10, rr = c & 1023;
            int d = rr >> 4, seg = (rr & 15) * 8;
            int bh = b * 16 + h0 + h;
            size_t base = ((size_t)(slot0 * 32 + bh) * 64 + d) * 512 + (t0 & 511);
            *reinterpret_cast<uint4*>(&Vtg[base + seg]) =
                *reinterpret_cast<const uint4*>(&T[(h * 64 + d) * TS + seg]);
        }
        // branch 1: stride-2 LDS gather, contiguous 128 B per (head,d)
        #pragma unroll
        for (int rep = 0; rep < 4; ++rep) {
            int c = rep * 256 + tid;
            int h = c >> 9, rr = c & 511;
            int d = rr >> 3, seg = rr & 7;
            int hh = h0 + h;
            int bh = b * 16 + hh;
            int p = hh & 1;
            const unsigned short* srw = &T[(h * 64 + d) * TS];
            unsigned short buf[8];
            #pragma unroll
            for (int j = 0; j < 8; ++j) buf[j] = srw[p + 2 * (seg * 8 + j)];
            size_t base = ((size_t)(slot1 * 32 + bh) * 64 + d) * 512 + ((t0 & 1023) >> 1);
            *reinterpret_cast<uint4*>(&Vtg[base + seg * 8]) = *reinterpret_cast<const uint4*>(buf);
        }
        // branch 2: stride-4 LDS gather, contiguous 64 B per (head,d)
        #pragma unroll
        for (int rep = 0; rep < 2; ++rep) {
            int c = rep * 256 + tid;
            int h = c >> 8, rr = c & 255;
            int d = rr >> 2, seg = rr & 3;
            int hh = h0 + h;
            int bh = b * 16 + hh;
            int p = hh & 3;
            const unsigned short* srw = &T[(h * 64 + d) * TS];
            unsigned short buf[8];
            #pragma unroll
            for (int j = 0; j < 8; ++j) buf[j] = srw[p + 4 * (seg * 8 + j)];
            size_t base = ((size_t)(slot2 * 32 + bh) * 64 + d) * 512 + ((t0 & 2047) >> 2);
            *reinterpret_cast<uint4*>(&Vtg[base + seg * 8]) = *reinterpret_cast<const uint4*>(buf);
        }
    }
}

// ---------------- dilated attention: swapped QK^T (S^T) + permuted-K staging => P stays in-register ----------------
__global__ __launch_bounds__(256, 3) void k_attn(
    const unsigned short* __restrict__ Qg,
    const unsigned short* __restrict__ Kg,
    const unsigned short* __restrict__ Vtg,
    unsigned short* __restrict__ Og,
    float* __restrict__ Lg)
{
    __shared__ unsigned short Ks[2][64 * 72];
    __shared__ unsigned short Vs[2][64 * 72];      // [d][kcol] (pre-transposed in global)

    int tid  = threadIdx.x;
    int lane = tid & 63, wv = tid >> 6;
    int quad = lane >> 4, l16 = lane & 15;
    int q8   = quad << 3;
    int pq = blockIdx.x, ys = blockIdx.y, bh = blockIdx.z;
    int jt_end = 2 * (3 - pq) + 1;    // 7 (pair 0,3) or 5 (pair 1,2)
    size_t sb = (size_t)(ys * 32 + bh) * (512 * 64);
    const unsigned short* qp = Qg + sb;
    const unsigned short* kp = Kg + sb;
    const unsigned short* vp = Vtg + sb;
    unsigned short* op = Og + sb;
    float* lp = Lg + (size_t)(ys * 32 + bh) * 512;

    int rw[2] = { pq * 128 + wv * 32, (3 - pq) * 128 + wv * 32 };

    // staging geometry: thread covers rows {srow, srow+32} cols sc8..sc8+7
    int srow = tid >> 3, sc8 = (tid & 7) * 8;
    // K-row permutation (bijective on 0..31): makes S^T output k-slots land in natural PV order.
    int prow = ((srow >> 2) & 1) * 16 + ((srow >> 3) & 3) * 4 + (srow & 3);
    uint4 kr[2], vr[2];
    {   // preload jt = 0
        #pragma unroll
        for (int s = 0; s < 2; ++s) {
            int row = s * 32 + srow;
            kr[s] = *reinterpret_cast<const uint4*>(&kp[(size_t)row * 64 + sc8]);
            vr[s] = *reinterpret_cast<const uint4*>(&vp[(size_t)row * 512 + sc8]);
        }
    }

    bf16x8 qf[2][2][2];
    #pragma unroll
    for (int qi = 0; qi < 2; ++qi)
        #pragma unroll
        for (int m16 = 0; m16 < 2; ++m16)
            #pragma unroll
            for (int kk = 0; kk < 2; ++kk)
                qf[qi][m16][kk] = *reinterpret_cast<const bf16x8*>(
                    &qp[(size_t)(rw[qi] + m16 * 16 + l16) * 64 + kk * 32 + quad * 8]);

    f32x4 acc[2][2][4] = {};
    float l4[2][2] = {};

    for (int jt = 0; jt <= jt_end; ++jt) {
        unsigned short* Kb = &Ks[jt & 1][0];
        unsigned short* Vb = &Vs[jt & 1][0];
        #pragma unroll
        for (int s = 0; s < 2; ++s) {
            *reinterpret_cast<uint4*>(&Kb[(s * 32 + prow) * 72 + sc8]) = kr[s];
            *reinterpret_cast<uint4*>(&Vb[(s * 32 + srow) * 72 + sc8]) = vr[s];
        }
        if (jt < jt_end) {   // prefetch next tile into regs; loads fly during compute below
            #pragma unroll
            for (int s = 0; s < 2; ++s) {
                int row = s * 32 + srow;
                kr[s] = *reinterpret_cast<const uint4*>(&kp[(size_t)((jt + 1) * 64 + row) * 64 + sc8]);
                vr[s] = *reinterpret_cast<const uint4*>(&vp[(size_t)row * 512 + (jt + 1) * 64 + sc8]);
            }
        }
        __syncthreads();     // dbuf: single barrier per jt

        #pragma unroll
        for (int qi = 0; qi < 2; ++qi) {
            #pragma unroll
            for (int m16 = 0; m16 < 2; ++m16) {
                int rowbase = rw[qi] + m16 * 16;
                if (jt * 64 > rowbase + 15) continue;

                // S^T = mfma(K, Q): lane holds S[q=l16][k = jt*64 + (nt>>1)*32 + quad*8 + (nt&1)*4 + ri]
                f32x4 sacc[4];
                __builtin_amdgcn_s_setprio(1);
                #pragma unroll
                for (int nt = 0; nt < 4; ++nt) {
                    bf16x8 b0 = *reinterpret_cast<const bf16x8*>(&Kb[(nt * 16 + l16) * 72 + quad * 8]);
                    bf16x8 b1 = *reinterpret_cast<const bf16x8*>(&Kb[(nt * 16 + l16) * 72 + 32 + quad * 8]);
                    f32x4 s4 = {};
                    s4 = __builtin_amdgcn_mfma_f32_16x16x32_bf16(b0, qf[qi][m16][0], s4, 0, 0, 0);
                    s4 = __builtin_amdgcn_mfma_f32_16x16x32_bf16(b1, qf[qi][m16][1], s4, 0, 0, 0);
                    sacc[nt] = s4;
                }
                __builtin_amdgcn_s_setprio(0);

                if (jt * 64 + 63 > rowbase) {
                    int qrow = rowbase + l16;
                    #pragma unroll
                    for (int nt = 0; nt < 4; ++nt)
                        #pragma unroll
                        for (int ri = 0; ri < 4; ++ri) {
                            int kj = jt * 64 + (nt >> 1) * 32 + (nt & 1) * 4 + q8 + ri;
                            if (kj > qrow) sacc[nt][ri] = -1e30f;
                        }
                }
                float ls = 0.f;
                #pragma unroll
                for (int nt = 0; nt < 4; ++nt)
                    #pragma unroll
                    for (int ri = 0; ri < 4; ++ri) {
                        float p = __builtin_amdgcn_exp2f(sacc[nt][ri]);
                        sacc[nt][ri] = p;
                        ls += p;
                    }
                l4[qi][m16] += ls;

                // P -> bf16 A-fragments: fully lane-local, naturally ordered (thanks to K permute)
                union { unsigned int u[4]; bf16x8 v; } p0u, p1u;
                asm("v_cvt_pk_bf16_f32 %0, %1, %2" : "=v"(p0u.u[0]) : "v"(sacc[0][0]), "v"(sacc[0][1]));
                asm("v_cvt_pk_bf16_f32 %0, %1, %2" : "=v"(p0u.u[1]) : "v"(sacc[0][2]), "v"(sacc[0][3]));
                asm("v_cvt_pk_bf16_f32 %0, %1, %2" : "=v"(p0u.u[2]) : "v"(sacc[1][0]), "v"(sacc[1][1]));
                asm("v_cvt_pk_bf16_f32 %0, %1, %2" : "=v"(p0u.u[3]) : "v"(sacc[1][2]), "v"(sacc[1][3]));
                asm("v_cvt_pk_bf16_f32 %0, %1, %2" : "=v"(p1u.u[0]) : "v"(sacc[2][0]), "v"(sacc[2][1]));
                asm("v_cvt_pk_bf16_f32 %0, %1, %2" : "=v"(p1u.u[1]) : "v"(sacc[2][2]), "v"(sacc[2][3]));
                asm("v_cvt_pk_bf16_f32 %0, %1, %2" : "=v"(p1u.u[2]) : "v"(sacc[3][0]), "v"(sacc[3][1]));
                asm("v_cvt_pk_bf16_f32 %0, %1, %2" : "=v"(p1u.u[3]) : "v"(sacc[3][2]), "v"(sacc[3][3]));

                __builtin_amdgcn_s_setprio(1);
                #pragma unroll
                for (int dt = 0; dt < 4; ++dt) {
                    bf16x8 v0 = *reinterpret_cast<const bf16x8*>(&Vb[(dt * 16 + l16) * 72 + quad * 8]);
                    bf16x8 v1 = *reinterpret_cast<const bf16x8*>(&Vb[(dt * 16 + l16) * 72 + 32 + quad * 8]);
                    f32x4 a4 = acc[qi][m16][dt];
                    a4 = __builtin_amdgcn_mfma_f32_16x16x32_bf16(p0u.v, v0, a4, 0, 0, 0);
                    a4 = __builtin_amdgcn_mfma_f32_16x16x32_bf16(p1u.v, v1, a4, 0, 0, 0);
                    acc[qi][m16][dt] = a4;
                }
                __builtin_amdgcn_s_setprio(0);
            }
        }
    }

    #pragma unroll
    for (int qi = 0; qi < 2; ++qi)
        #pragma unroll
        for (int m16 = 0; m16 < 2; ++m16) {
            int rowb = rw[qi] + m16 * 16;
            float L = l4[qi][m16];
            L += __shfl_xor(L, 16);
            L += __shfl_xor(L, 32);       // full row sum for q-row rowb + l16 (dup across quads)
            float inv[4];
            #pragma unroll
            for (int ri = 0; ri < 4; ++ri)
                inv[ri] = 1.f / __shfl(L, quad * 4 + ri);
            #pragma unroll
            for (int dt = 0; dt < 4; ++dt)
                #pragma unroll
                for (int ri = 0; ri < 4; ++ri) {
                    int row = rowb + quad * 4 + ri;
                    op[(size_t)row * 64 + dt * 16 + l16] = f2bf(acc[qi][m16][dt][ri] * inv[ri]);
                }
            if (lane < 16)
                lp[rowb + l16] = __logf(L);
        }
}

// ---------------- combine branches via LSE weights ----------------
__global__ void k_combine(const unsigned short* __restrict__ Og,
                          const float* __restrict__ Lg,
                          unsigned short* __restrict__ yb)
{
    int g   = blockIdx.x * blockDim.x + threadIdx.x;
    int row = g >> 3;
    int d0  = (g & 7) * 8;
    int bh = row >> 12, t = row & 4095;
    int b = bh >> 4, h = bh & 15;

    int slot0 = t >> 9,         idx0 = t & 511;
    int slot1 = 8 + (t >> 10),  idx1 = (t & 1023) >> 1;
    int slot2 = 12 + (t >> 11), idx2 = (t & 2047) >> 2;
    size_t r0 = (size_t)(slot0 * 32 + bh) * 512 + idx0;
    size_t r1 = (size_t)(slot1 * 32 + bh) * 512 + idx1;
    size_t r2 = (size_t)(slot2 * 32 + bh) * 512 + idx2;
    bool c1 = ((t ^ h) & 1) == 0;
    bool c2 = ((t ^ h) & 3) == 0;

    float L0 = Lg[r0];
    float L1 = c1 ? Lg[r1] : -1e30f;
    float L2 = c2 ? Lg[r2] : -1e30f;
    float m  = fmaxf(L0, fmaxf(L1, L2));
    float w0 = __expf(L0 - m), w1 = __expf(L1 - m), w2 = __expf(L2 - m);
    float inv = 1.f / (w0 + w1 + w2);

    uint4 v0 = *reinterpret_cast<const uint4*>(&Og[r0 * 64 + d0]);
    uint4 v1 = *reinterpret_cast<const uint4*>(&Og[r1 * 64 + d0]);
    uint4 v2 = *reinterpret_cast<const uint4*>(&Og[r2 * 64 + d0]);
    const unsigned short* p0 = reinterpret_cast<const unsigned short*>(&v0);
    const unsigned short* p1 = reinterpret_cast<const unsigned short*>(&v1);
    const unsigned short* p2 = reinterpret_cast<const unsigned short*>(&v2);
    unsigned short o[8];
    #pragma unroll
    for (int u = 0; u < 8; ++u)
        o[u] = f2bf((w0 * bf2f(p0[u]) + w1 * bf2f(p1[u]) + w2 * bf2f(p2[u])) * inv);
    size_t yidx = (((size_t)b * 4096 + t) * 1024) + (size_t)h * 64 + d0;
    *reinterpret_cast<uint4*>(&yb[yidx]) = *reinterpret_cast<const uint4*>(o);
}

extern "C" void kernel_launch(void* const* d_in, const int* in_sizes, int n_in,
                              void* d_out, int out_size, void* d_ws, size_t ws_size,
                              hipStream_t stream)
{
    const float* x        = (const float*)d_in[0];
    const float* c_attn_w = (const float*)d_in[1];
    const float* c_attn_b = (const float*)d_in[2];
    const float* q_w      = (const float*)d_in[3];
    const float* q_b      = (const float*)d_in[4];
    const float* k_w      = (const float*)d_in[5];
    const float* k_b      = (const float*)d_in[6];
    const float* v_w      = (const float*)d_in[7];
    const float* v_b      = (const float*)d_in[8];
    const float* o_w      = (const float*)d_in[9];
    const float* o_b      = (const float*)d_in[10];

    char* ws = (char*)d_ws;
    size_t off = 0;
    auto alloc = [&](size_t bytes) -> char* {
        char* p = ws + off; off += (bytes + 255) & ~(size_t)255; return p;
    };
    const size_t GSZ = 14ull * 32 * 512 * 64;
    unsigned short* xb    = (unsigned short*)alloc(8192ull * 1024 * 2);
    unsigned short* WcB   = (unsigned short*)alloc(1024ull * 3072 * 2);   // c_attn_w bf16, untransposed
    unsigned short* wqT   = (unsigned short*)alloc(1024ull * 1024 * 2);   // q/k/v contiguous
    unsigned short* wkT   = (unsigned short*)alloc(1024ull * 1024 * 2);
    unsigned short* wvT   = (unsigned short*)alloc(1024ull * 1024 * 2);
    unsigned short* woT   = (unsigned short*)alloc(1024ull * 1024 * 2);
    unsigned short* Weff  = (unsigned short*)alloc(3ull * 1024 * 1024 * 2);
    float*          beff  = (float*)alloc(3ull * 1024 * 4);
    unsigned short* Qg    = (unsigned short*)alloc(GSZ * 2);
    unsigned short* Kg    = (unsigned short*)alloc(GSZ * 2);
    unsigned short* Vtg   = (unsigned short*)alloc(GSZ * 2);
    unsigned short* Og    = (unsigned short*)alloc(GSZ * 2);
    float*          Lg    = (float*)alloc(14ull * 32 * 512 * 4);
    unsigned short* yb    = xb;   // alias: xb dead after k_gemm3
    (void)wkT; (void)wvT;

    // 1. prep: casts (x, c_attn_w) + transpose-cast q/k/v/o weights -- ONE dispatch
    k_prep<<<15360, 256, 0, stream>>>(x, xb, c_attn_w, WcB, q_w, k_w, v_w, o_w, wqT, wkT, wvT, woT);
    // 2. weight + bias fold -- ONE dispatch
    k_foldwb<<<960, 256, 0, stream>>>(wqT, WcB, Weff, c_attn_b, q_b, k_b, v_b, beff);
    // 3. fused projections: x -> gathered Q/K/V^T (BK=64, LDS-bounced epilogue, XCD swizzle)
    k_gemm3<<<dim3(8, 64, 3), 256, 0, stream>>>(xb, Weff, beff, Qg, Kg, Vtg);
    // 4. attention (swapped-QK in-register P, dbuf K/V, single barrier per tile)
    k_attn<<<dim3(2, 14, 32), 256, 0, stream>>>(Qg, Kg, Vtg, Og, Lg);
    // 5. combine -> y
    k_combine<<<4096, 256, 0, stream>>>(Og, Lg, yb);
    // 6. out = y @ o_w + o_b (fp32, BK=64)
    k_gemm<<<dim3(8, 64), 256, 0, stream>>>(yb, 1024, woT, 1024, o_b, d_out, 8192, 1024, 1024, 2, 1.f);
}